// Round 10
// baseline (765.332 us; speedup 1.0000x reference)
//
#include <hip/hip_runtime.h>

#define Bb 8
#define Cc 128
#define Hh 128
#define Ww 128
#define HW 16384
#define CHW (Cc*HW)
#define NHW (Bb*HW)
#define CH 16
#define EPS 1e-5f
#define NSLICE 16

typedef __attribute__((ext_vector_type(8))) short bf16x8;
typedef __attribute__((ext_vector_type(4))) float f32x4;

static __device__ __forceinline__ short f2b(float f) {
  unsigned u = __float_as_uint(f);
  unsigned lsb = (u >> 16) & 1;
  return (short)((u + 0x7fffu + lsb) >> 16);
}
static __device__ __forceinline__ float b2f(short s) {
  return __uint_as_float(((unsigned)(unsigned short)s) << 16);
}

// per-wave 16-lane butterfly + atomic stats update, SHARDED 16 ways by blockIdx
static __device__ __forceinline__ void stats_epilogue(
    float* __restrict__ statp, f32x4 acc[4][4], int co0, int quad, int lm)
{
  statp += (blockIdx.x & (NSLICE-1)) * 768;
  #pragma unroll
  for (int i = 0; i < 4; ++i) {
    f32x4 s = acc[i][0] + acc[i][1] + acc[i][2] + acc[i][3];
    f32x4 q = acc[i][0]*acc[i][0] + acc[i][1]*acc[i][1]
            + acc[i][2]*acc[i][2] + acc[i][3]*acc[i][3];
    #pragma unroll
    for (int m = 1; m < 16; m <<= 1) {
      #pragma unroll
      for (int e = 0; e < 4; ++e) {
        s[e] += __shfl_xor(s[e], m);
        q[e] += __shfl_xor(q[e], m);
      }
    }
    if (lm == 0) {
      int co = co0 + i*16 + quad*4;
      #pragma unroll
      for (int e = 0; e < 4; ++e) {
        atomicAdd(&statp[co + e], s[e]);
        atomicAdd(&statp[128 + co + e], q[e]);
      }
    }
  }
}

// ---------------- LayerNorm over channel dim ----------------
__global__ __launch_bounds__(256) void k_ln(const float* __restrict__ x,
    const float* __restrict__ g, const float* __restrict__ be,
    float* __restrict__ y)
{
  int p = blockIdx.x*256 + threadIdx.x;
  int b = p >> 14, hw = p & 16383;
  const float* xp = x + (long)b*CHW + hw;
  float s = 0.f, q = 0.f;
  for (int c = 0; c < Cc; ++c) { float v = xp[c*HW]; s += v; q += v*v; }
  float mu = s * (1.f/Cc);
  float var = q * (1.f/Cc) - mu*mu;
  float rstd = rsqrtf(var + EPS);
  float* yp = y + (long)b*CHW + hw;
  for (int c = 0; c < Cc; ++c) {
    float v = xp[c*HW];
    yp[c*HW] = (v - mu) * rstd * g[c] + be[c];
  }
}

// ---------------- 3x3 weight: [co][ci][tap] fp32 -> [tap][co][ci] bf16 ----------------
__global__ __launch_bounds__(256) void k_reorg3b(const float* __restrict__ Wt, short* __restrict__ out)
{
  int idx = blockIdx.x*256 + threadIdx.x;
  int tap = idx >> 14, r = idx & 16383;
  out[idx] = f2b(Wt[r*9 + tap]);
}

__global__ __launch_bounds__(256) void k_cast(const float* __restrict__ in, short* __restrict__ out)
{
  int i = blockIdx.x*256 + threadIdx.x;
  out[i] = f2b(in[i]);
}

__global__ __launch_bounds__(256) void k_zero(float* p, int n)
{
  int i = blockIdx.x*256 + threadIdx.x;
  if (i < n) p[i] = 0.f;
}

// ---------------- NCHW fp32 -> NHWC bf16 ----------------
__global__ __launch_bounds__(256) void k_nhwc(const float* __restrict__ in, short* __restrict__ out)
{
  __shared__ float Ls[32][33];
  int bid = blockIdx.x;
  int hwt = bid & 511, c4 = (bid>>9)&3, b = bid>>11;
  int hw0 = hwt << 5, c0 = c4 << 5;
  int t = threadIdx.x;
  int hl = t & 31, cl = t >> 5;
  const float* p = in + (long)b*CHW + hw0;
  for (int r = cl; r < 32; r += 8)
    Ls[r][hl] = p[(long)(c0+r)*HW + hl];
  __syncthreads();
  short* q = out + ((long)b*HW + hw0)*Cc + c0;
  int ccl = t & 31, hl0 = t >> 5;
  for (int r = hl0; r < 32; r += 8)
    q[(long)r*Cc + ccl] = f2b(Ls[ccl][r]);
}

// ---------------- NCHW bf16 -> NHWC bf16 (no re-round) ----------------
__global__ __launch_bounds__(256) void k_nhwcb(const short* __restrict__ in, short* __restrict__ out)
{
  __shared__ short Ls[32][34];
  int bid = blockIdx.x;
  int hwt = bid & 511, c4 = (bid>>9)&3, b = bid>>11;
  int hw0 = hwt << 5, c0 = c4 << 5;
  int t = threadIdx.x;
  int hl = t & 31, cl = t >> 5;
  const short* p = in + (long)b*CHW + hw0;
  for (int r = cl; r < 32; r += 8)
    Ls[r][hl] = p[(long)(c0+r)*HW + hl];
  __syncthreads();
  short* q = out + ((long)b*HW + hw0)*Cc + c0;
  int ccl = t & 31, hl0 = t >> 5;
  for (int r = hl0; r < 32; r += 8)
    q[(long)r*Cc + ccl] = Ls[ccl][r];
}

// ---------------- MFMA conv, dilated 3x3, full-K LDS tiles, NHWC fp32 output ----
__global__ __launch_bounds__(256,2) void k_mconv(const short* __restrict__ X,
    const short* __restrict__ W, float* __restrict__ Y, int k3, int dil,
    float* __restrict__ statp)
{
  __shared__ short Ws[128*136];
  __shared__ short Xs[152*136];
  int b = blockIdx.x >> 7, h = blockIdx.x & 127;
  int t = threadIdx.x;
  int wave = t >> 6, lane = t & 63;
  int co0 = (wave >> 1) << 6, sp0 = (wave & 1) << 6;
  int lm = lane & 15, quad = lane >> 4;
  f32x4 acc[4][4];
  #pragma unroll
  for (int i = 0; i < 4; ++i)
    #pragma unroll
    for (int j = 0; j < 4; ++j) acc[i][j] = (f32x4){0.f,0.f,0.f,0.f};
  int half = k3 >> 1;

  {
    f32x4 z = {0.f,0.f,0.f,0.f};
    for (int i = t; i < 408; i += 256) {        // 24 halo rows x 17 f32x4
      int r = i / 17, o = i - r*17;
      int row = r < 12 ? r : r + 128;
      *(f32x4*)(Xs + row*136 + o*8) = z;
    }
  }

  for (int kh = 0; kh < k3; ++kh) {
    int hs = h + (kh - half)*dil;
    if ((unsigned)hs >= (unsigned)Hh) continue;
    __syncthreads();
    {
      const short* xr = X + ((long)(b*Hh + hs)*Ww)*Cc;
      #pragma unroll
      for (int it = 0; it < 8; ++it) {
        int i = t + it*256;
        int row = i >> 4, off = (i & 15) << 3;
        *(f32x4*)(Xs + (12 + row)*136 + off) = *(const f32x4*)(xr + (long)row*Cc + off);
      }
    }
    for (int kw = 0; kw < k3; ++kw) {
      int dw = (kw - half)*dil;
      if (kw) __syncthreads();
      {
        const short* wt = W + (kh*k3 + kw)*16384;
        #pragma unroll
        for (int it = 0; it < 8; ++it) {
          int i = t + it*256;
          int row = i >> 4, off = (i & 15) << 3;
          *(f32x4*)(Ws + row*136 + off) = *(const f32x4*)(wt + (long)row*128 + off);
        }
      }
      __syncthreads();
      int xrow0 = 12 + dw + sp0;
      for (int kc = 0; kc < 4; ++kc) {
        int k0 = kc << 5;
        bf16x8 af[4], bfr[4];
        #pragma unroll
        for (int i = 0; i < 4; ++i)
          af[i] = *(const bf16x8*)(Ws + (co0 + i*16 + lm)*136 + k0 + quad*8);
        #pragma unroll
        for (int j = 0; j < 4; ++j)
          bfr[j] = *(const bf16x8*)(Xs + (xrow0 + j*16 + lm)*136 + k0 + quad*8);
        #pragma unroll
        for (int i = 0; i < 4; ++i)
          #pragma unroll
          for (int j = 0; j < 4; ++j)
            acc[i][j] = __builtin_amdgcn_mfma_f32_16x16x32_bf16(af[i], bfr[j], acc[i][j], 0, 0, 0);
      }
    }
  }
  float* yb = Y + ((long)(b*Hh + h)*Ww)*Cc;
  #pragma unroll
  for (int i = 0; i < 4; ++i) {
    int co = co0 + i*16 + quad*4;
    #pragma unroll
    for (int j = 0; j < 4; ++j) {
      int wc = sp0 + j*16 + lm;
      *(f32x4*)(yb + (long)wc*Cc + co) = acc[i][j];
    }
  }
  if (statp) stats_epilogue(statp, acc, co0, quad, lm);
}

// ---------------- MFMA 1x1 conv: weights in LDS, X fragments direct from global ----
__global__ __launch_bounds__(256,4) void k_mconv1(const short* __restrict__ X,
    const short* __restrict__ W, const float* __restrict__ res,
    float* __restrict__ Y, int nhwc, float* __restrict__ statp)
{
  __shared__ short Ws[128*136];
  int b = blockIdx.x >> 7, h = blockIdx.x & 127;
  int t = threadIdx.x;
  int wave = t >> 6, lane = t & 63;
  int co0 = (wave >> 1) << 6, sp0 = (wave & 1) << 6;
  int lm = lane & 15, quad = lane >> 4;
  #pragma unroll
  for (int it = 0; it < 8; ++it) {
    int i = t + it*256;
    int row = i >> 4, off = (i & 15) << 3;
    *(f32x4*)(Ws + row*136 + off) = *(const f32x4*)(W + (long)row*128 + off);
  }
  f32x4 acc[4][4];
  #pragma unroll
  for (int i = 0; i < 4; ++i)
    #pragma unroll
    for (int j = 0; j < 4; ++j) acc[i][j] = (f32x4){0.f,0.f,0.f,0.f};
  const short* xr = X + ((long)(b*Hh + h)*Ww)*Cc;
  __syncthreads();
  #pragma unroll
  for (int kc = 0; kc < 4; ++kc) {
    int k0 = kc << 5;
    bf16x8 af[4], bfr[4];
    #pragma unroll
    for (int j = 0; j < 4; ++j)
      bfr[j] = *(const bf16x8*)(xr + (long)(sp0 + j*16 + lm)*Cc + k0 + quad*8);
    #pragma unroll
    for (int i = 0; i < 4; ++i)
      af[i] = *(const bf16x8*)(Ws + (co0 + i*16 + lm)*136 + k0 + quad*8);
    #pragma unroll
    for (int i = 0; i < 4; ++i)
      #pragma unroll
      for (int j = 0; j < 4; ++j)
        acc[i][j] = __builtin_amdgcn_mfma_f32_16x16x32_bf16(af[i], bfr[j], acc[i][j], 0, 0, 0);
  }
  if (nhwc) {
    float* yb = Y + ((long)(b*Hh + h)*Ww)*Cc;
    #pragma unroll
    for (int i = 0; i < 4; ++i) {
      int co = co0 + i*16 + quad*4;
      #pragma unroll
      for (int j = 0; j < 4; ++j) {
        int wc = sp0 + j*16 + lm;
        *(f32x4*)(yb + (long)wc*Cc + co) = acc[i][j];
      }
    }
    if (statp) stats_epilogue(statp, acc, co0, quad, lm);
  } else {
    __syncthreads();                       // all waves done reading Ws
    float* scr = (float*)Ws + wave*320;    // 16 rows x stride 20 f32, wave-private
    int co_l = lane >> 2, wq = (lane & 3) << 2;
    #pragma unroll
    for (int i = 0; i < 4; ++i) {
      #pragma unroll
      for (int j = 0; j < 4; ++j) {
        #pragma unroll
        for (int r = 0; r < 4; ++r)
          scr[(quad*4 + r)*20 + lm] = acc[i][j][r];
        f32x4 vv = *(f32x4*)(scr + co_l*20 + wq);
        int co = co0 + i*16 + co_l;
        int wc = sp0 + j*16 + wq;
        long idx = ((long)(b*Cc + co)*Hh + h)*Ww + wc;
        if (res) vv += *(const f32x4*)(res + idx);
        *(f32x4*)(Y + idx) = vv;
      }
    }
  }
}

// ---------------- BN finalize: sum 16 slices -> per-channel scale/offset ----------------
__global__ __launch_bounds__(128) void k_bnfin(const float* __restrict__ stats,
    const float* __restrict__ g1, const float* __restrict__ be1,
    const float* __restrict__ g2, const float* __restrict__ be2,
    const float* __restrict__ g3, const float* __restrict__ be3,
    float* __restrict__ so)
{
  int c = threadIdx.x;
  const float inv = 1.f/(float)NHW;
  const float* gs[3] = {g1, g2, g3};
  const float* bs[3] = {be1, be2, be3};
  #pragma unroll
  for (int tsel = 0; tsel < 3; ++tsel) {
    float su = 0.f, qu = 0.f;
    for (int sl = 0; sl < NSLICE; ++sl) {
      su += stats[sl*768 + tsel*256 + c];
      qu += stats[sl*768 + tsel*256 + 128 + c];
    }
    float mu = su*inv;
    float var = qu*inv - mu*mu;
    float s = rsqrtf(var + EPS)*gs[tsel][c];
    so[tsel*256 + c] = s;
    so[tsel*256 + 128 + c] = bs[tsel][c] - mu*s;
  }
}

// ---------------- BN apply + relu, sum three branches (NHWC in) -> sb bf16 NHWC ----
__global__ __launch_bounds__(256) void k_bnapply(const float* __restrict__ y1,
    const float* __restrict__ y2, const float* __restrict__ y3,
    const float* __restrict__ so, short* __restrict__ sb)
{
  long e = ((long)blockIdx.x*256 + threadIdx.x) * 8;
  int c = (int)(e & 127);
  f32x4 s1a = *(const f32x4*)(so + c),        s1b = *(const f32x4*)(so + c + 4);
  f32x4 o1a = *(const f32x4*)(so + 128 + c),  o1b = *(const f32x4*)(so + 132 + c);
  f32x4 s2a = *(const f32x4*)(so + 256 + c),  s2b = *(const f32x4*)(so + 260 + c);
  f32x4 o2a = *(const f32x4*)(so + 384 + c),  o2b = *(const f32x4*)(so + 388 + c);
  f32x4 s3a = *(const f32x4*)(so + 512 + c),  s3b = *(const f32x4*)(so + 516 + c);
  f32x4 o3a = *(const f32x4*)(so + 640 + c),  o3b = *(const f32x4*)(so + 644 + c);
  f32x4 v1a = *(const f32x4*)(y1 + e), v1b = *(const f32x4*)(y1 + e + 4);
  f32x4 v2a = *(const f32x4*)(y2 + e), v2b = *(const f32x4*)(y2 + e + 4);
  f32x4 v3a = *(const f32x4*)(y3 + e), v3b = *(const f32x4*)(y3 + e + 4);
  float r[8];
  #pragma unroll
  for (int k = 0; k < 4; ++k) {
    r[k] = fmaxf(fmaf(v1a[k], s1a[k], o1a[k]), 0.f)
         + fmaxf(fmaf(v2a[k], s2a[k], o2a[k]), 0.f)
         + fmaxf(fmaf(v3a[k], s3a[k], o3a[k]), 0.f);
    r[4+k] = fmaxf(fmaf(v1b[k], s1b[k], o1b[k]), 0.f)
           + fmaxf(fmaf(v2b[k], s2b[k], o2b[k]), 0.f)
           + fmaxf(fmaf(v3b[k], s3b[k], o3b[k]), 0.f);
  }
  int4 o;
  o.x = ((int)(unsigned short)f2b(r[1])<<16) | (unsigned short)f2b(r[0]);
  o.y = ((int)(unsigned short)f2b(r[3])<<16) | (unsigned short)f2b(r[2]);
  o.z = ((int)(unsigned short)f2b(r[5])<<16) | (unsigned short)f2b(r[4]);
  o.w = ((int)(unsigned short)f2b(r[7])<<16) | (unsigned short)f2b(r[6]);
  *(int4*)(sb + e) = o;
}

// ---------------- six depthwise branches summed, LDS-tiled stencil, bf16 out ----
__global__ __launch_bounds__(256) void k_dw2(const float* __restrict__ X,
    const float* __restrict__ w1, const float* __restrict__ b1,
    const float* __restrict__ w2, const float* __restrict__ b2,
    const float* __restrict__ w3, const float* __restrict__ b3,
    const float* __restrict__ w4, const float* __restrict__ b4,
    const float* __restrict__ w5, const float* __restrict__ b5,
    const float* __restrict__ w6, const float* __restrict__ b6,
    short* __restrict__ Y)
{
  __shared__ float Ls[38][136];
  int bid = blockIdx.x;
  int tile = bid & 3, plane = bid >> 2;
  int c = plane & 127;
  int h0 = tile << 5;
  int t = threadIdx.x;

  float hcoef[7], vcoef[7], k9[9];
  #pragma unroll
  for (int d = 0; d < 7; ++d) { hcoef[d] = w5[c*7+d]; vcoef[d] = w6[c*7+d]; }
  #pragma unroll
  for (int d = 1; d < 6; ++d) { hcoef[d] += w1[c*5+d-1]; vcoef[d] += w2[c*5+d-1]; }
  hcoef[3] += w3[c];
  #pragma unroll
  for (int k = 0; k < 9; ++k) k9[k] = w4[c*9+k];
  float bias = b1[c]+b2[c]+b3[c]+b4[c]+b5[c]+b6[c];

  const float* xp = X + (long)plane*HW;

  f32x4* lz = (f32x4*)&Ls[0][0];
  for (int i = t; i < 1292; i += 256) lz[i] = (f32x4){0.f,0.f,0.f,0.f};
  __syncthreads();
  for (int i = t; i < 1216; i += 256) {
    int r = i >> 5, cg = (i & 31) << 2;
    int h = h0 - 3 + r;
    if ((unsigned)h < 128u)
      *(f32x4*)&Ls[r][4 + cg] = *(const f32x4*)(xp + h*128 + cg);
  }
  __syncthreads();

  int g = t & 31, rs = t >> 5;
  int w0 = g << 2;
  short* Yp = Y + (long)plane*HW;

  for (int ro = 0; ro < 4; ++ro) {
    int lr = rs + (ro << 3);
    int R = lr + 3;
    f32x4 a0 = *(const f32x4*)&Ls[R][w0];
    f32x4 a1 = *(const f32x4*)&Ls[R][w0+4];
    f32x4 a2 = *(const f32x4*)&Ls[R][w0+8];
    f32x4 u0 = *(const f32x4*)&Ls[R-1][w0];
    f32x4 u1 = *(const f32x4*)&Ls[R-1][w0+4];
    f32x4 u2 = *(const f32x4*)&Ls[R-1][w0+8];
    f32x4 d0 = *(const f32x4*)&Ls[R+1][w0];
    f32x4 d1 = *(const f32x4*)&Ls[R+1][w0+4];
    f32x4 d2 = *(const f32x4*)&Ls[R+1][w0+8];
    f32x4 v3u = *(const f32x4*)&Ls[R-3][w0+4];
    f32x4 v2u = *(const f32x4*)&Ls[R-2][w0+4];
    f32x4 v2d = *(const f32x4*)&Ls[R+2][w0+4];
    f32x4 v3d = *(const f32x4*)&Ls[R+3][w0+4];

    float cr[12], ur[12], dr[12];
    #pragma unroll
    for (int k = 0; k < 4; ++k) {
      cr[k] = a0[k]; cr[4+k] = a1[k]; cr[8+k] = a2[k];
      ur[k] = u0[k]; ur[4+k] = u1[k]; ur[8+k] = u2[k];
      dr[k] = d0[k]; dr[4+k] = d1[k]; dr[8+k] = d2[k];
    }

    float o[4];
    #pragma unroll
    for (int j = 0; j < 4; ++j) {
      float acc = bias;
      #pragma unroll
      for (int d = 0; d < 7; ++d) acc = fmaf(hcoef[d], cr[j+d+1], acc);
      acc = fmaf(vcoef[0], v3u[j], acc);
      acc = fmaf(vcoef[1], v2u[j], acc);
      acc = fmaf(vcoef[2], ur[j+4], acc);
      acc = fmaf(vcoef[3], cr[j+4], acc);
      acc = fmaf(vcoef[4], dr[j+4], acc);
      acc = fmaf(vcoef[5], v2d[j], acc);
      acc = fmaf(vcoef[6], v3d[j], acc);
      #pragma unroll
      for (int kw = 0; kw < 3; ++kw) {
        acc = fmaf(k9[kw],   ur[j+3+kw], acc);
        acc = fmaf(k9[3+kw], cr[j+3+kw], acc);
        acc = fmaf(k9[6+kw], dr[j+3+kw], acc);
      }
      o[j] = acc;
    }
    int2 ov;
    ov.x = ((int)(unsigned short)f2b(o[1])<<16) | (unsigned short)f2b(o[0]);
    ov.y = ((int)(unsigned short)f2b(o[3])<<16) | (unsigned short)f2b(o[2]);
    *(int2*)(Yp + (h0 + lr)*128 + w0) = ov;
  }
}

// ---------------- finalize: acc -> 1/max(sqrt(acc),1e-12), in place ----------------
__global__ __launch_bounds__(256) void k_finw(float* __restrict__ p)
{
  int i = blockIdx.x*256 + threadIdx.x;
  float v = p[i];
  p[i] = 1.f/fmaxf(sqrtf(v), 1e-12f);
}

// ---------------- fused transpose+cast+NORM: per 32x32 tile of out1/out2 produce
// out?T (transposed bf16) AND out?H; ALSO accumulate row/col square-sums into
// the norm accumulators (invn1h for out1 rows; invn1w/invn2w for cols).
// 64 contributors per accumulator address (16 c x 4 tiles) -> safe atomic regime.
__global__ __launch_bounds__(256) void k_thx(const float* __restrict__ out1,
    const float* __restrict__ out2,
    short* __restrict__ out1T, short* __restrict__ out2T,
    short* __restrict__ out1H, short* __restrict__ out2H,
    float* __restrict__ n1h, float* __restrict__ n1w, float* __restrict__ n2w)
{
  __shared__ float Ls[32][33];
  int bid = blockIdx.x;
  int wt = bid&3, ht=(bid>>2)&3, c=(bid>>4)&127, b=(bid>>11)&7, src=bid>>14;
  const float* in = (src ? out2 : out1) + (long)(b*128+c)*16384;
  long tbase = ((long)(b*8 + (c>>4))*128)*2048 + (c&15)*128;
  short* pT = (src ? out2T : out1T) + tbase;
  short* pH; long hstr;
  if (src) { pH = out2H + (long)(b*128+c)*16384; hstr = 128; }
  else     { pH = out1H + tbase;                 hstr = 2048; }
  int h0 = ht*32, w0 = wt*32;
  int t = threadIdx.x, li = t&31, r0 = t>>5;
  for (int r = r0; r < 32; r += 8)
    Ls[r][li] = in[(h0+r)*128 + w0 + li];
  __syncthreads();
  // norm partials: threads 0-31 row-sums (h-norm, out1 only); 32-63 col-sums
  int bhbase = (b*8 + (c>>4))*128;
  if (t < 32) {
    if (!src) {
      float s = 0.f;
      for (int k = 0; k < 32; ++k) { float v = Ls[t][k]; s += v*v; }
      atomicAdd(&n1h[bhbase + h0 + t], s);
    }
  } else if (t < 64) {
    int w = t - 32;
    float s = 0.f;
    for (int k = 0; k < 32; ++k) { float v = Ls[k][w]; s += v*v; }
    atomicAdd((src ? n2w : n1w) + bhbase + w0 + w, s);
  }
  for (int r = r0; r < 32; r += 8) {
    pT[(long)(w0+r)*2048 + h0 + li] = f2b(Ls[li][r]);
    pH[(long)(h0+r)*hstr + w0 + li] = f2b(Ls[r][li]);
  }
}

// ---------------- MFMA attention S + softmax -> A1/A2 (bf16 row-major) ----------------
// grid 256 = type(2) x bh(64) x rowhalf(2). Block: 64 rows x 128 cols, K=2048.
// 4 waves x 16 rows; each softmax row lives in one wave. Same kc/ks accumulation
// order as the 128-row version -> bit-identical S and softmax.
__global__ __launch_bounds__(256) void k_attnS_m(
    const short* __restrict__ out1T, const short* __restrict__ out2T,
    const short* __restrict__ out1H,
    const float* __restrict__ invn1h, const float* __restrict__ invn1w,
    const float* __restrict__ invn2w,
    short* __restrict__ A1b, short* __restrict__ A2b)
{
  __shared__ short As[64*72];
  __shared__ short Bs[128*72];
  int bid = blockIdx.x;
  int rh = bid & 1, bh = (bid >> 1) & 63, type = bid >> 7;
  const short* Aop = (type ? out1T : out2T) + (long)bh*262144 + (long)rh*131072;
  const short* Bop = (type ? out2T : out1H) + (long)bh*262144;
  const float* invrow = (type ? invn1w : invn2w) + bh*128 + rh*64;
  const float* invcol = (type ? invn2w : invn1h) + bh*128;
  short* Aout = (type ? A2b : A1b) + (long)bh*16384 + rh*8192;
  int t = threadIdx.x;
  int wave = t >> 6, lane = t & 63, lm = lane & 15, quad = lane >> 4;
  int m0 = wave << 4;
  f32x4 acc[8];
  #pragma unroll
  for (int j = 0; j < 8; ++j) acc[j] = (f32x4){0.f,0.f,0.f,0.f};
  for (int kc = 0; kc < 32; ++kc) {
    int k0 = kc << 6;
    __syncthreads();
    #pragma unroll
    for (int i = 0; i < 2; ++i) {
      int e = t + i*256;
      int row = e >> 3, off = (e & 7) << 3;
      *(float4*)(As + row*72 + off) = *(const float4*)(Aop + (long)row*2048 + k0 + off);
    }
    #pragma unroll
    for (int i = 0; i < 4; ++i) {
      int e = t + i*256;
      int row = e >> 3, off = (e & 7) << 3;
      *(float4*)(Bs + row*72 + off) = *(const float4*)(Bop + (long)row*2048 + k0 + off);
    }
    __syncthreads();
    #pragma unroll
    for (int ks = 0; ks < 64; ks += 32) {
      bf16x8 af, bfj[8];
      af = *(const bf16x8*)(As + (m0 + lm)*72 + ks + quad*8);
      #pragma unroll
      for (int j = 0; j < 8; ++j)
        bfj[j] = *(const bf16x8*)(Bs + (j*16 + lm)*72 + ks + quad*8);
      #pragma unroll
      for (int j = 0; j < 8; ++j)
        acc[j] = __builtin_amdgcn_mfma_f32_16x16x32_bf16(af, bfj[j], acc[j], 0, 0, 0);
    }
  }
  float colv[8];
  #pragma unroll
  for (int j = 0; j < 8; ++j) colv[j] = invcol[j*16 + lm];
  #pragma unroll
  for (int r = 0; r < 4; ++r) {
    int row = m0 + quad*4 + r;
    float rs = invrow[row];
    float sv[8];
    float mx = -1e30f;
    #pragma unroll
    for (int j = 0; j < 8; ++j) {
      sv[j] = acc[j][r] * rs * colv[j];
      mx = fmaxf(mx, sv[j]);
    }
    mx = fmaxf(mx, __shfl_xor(mx, 1));
    mx = fmaxf(mx, __shfl_xor(mx, 2));
    mx = fmaxf(mx, __shfl_xor(mx, 4));
    mx = fmaxf(mx, __shfl_xor(mx, 8));
    float sum = 0.f;
    #pragma unroll
    for (int j = 0; j < 8; ++j) { sv[j] = __expf(sv[j] - mx); sum += sv[j]; }
    sum += __shfl_xor(sum, 1);
    sum += __shfl_xor(sum, 2);
    sum += __shfl_xor(sum, 4);
    sum += __shfl_xor(sum, 8);
    float inv = 1.f/sum;
    #pragma unroll
    for (int j = 0; j < 8; ++j)
      Aout[row*128 + j*16 + lm] = f2b(sv[j]*inv);
  }
}

// ---------------- fused o34: o3 + o4 + q2 + q1, single bf16 write ----------------
__global__ __launch_bounds__(256) void k_o34f(
    const short* __restrict__ A1b, const short* __restrict__ out1T,
    const short* __restrict__ out1H, const float* __restrict__ invn1w,
    const short* __restrict__ out2H, const short* __restrict__ A2b,
    const float* __restrict__ out2, const float* __restrict__ invn2w,
    short* __restrict__ o34b)
{
  __shared__ short As[128*72];
  __shared__ short Bs[128*72];
  int bid = blockIdx.x;
  int cf = bid & 127, b = bid >> 7;
  int hd = cf >> 4, c = cf & 15;
  int bh = b*8 + hd;
  const short* A0 = A1b + (long)bh*16384;              // [h][k] stride 128
  const short* B0 = out1T + (long)bh*262144 + c*128;   // [w][k] stride 2048
  const short* A1_ = out2H + (long)(b*128 + cf)*16384; // [h][k] stride 128
  const short* B1_ = A2b + (long)bh*16384;             // [w][k] stride 128
  const short* R = out1H + (long)bh*262144 + c*128;    // q2 operand, stride 2048
  const float* o2p = out2 + (long)(b*128 + cf)*16384;  // q1 operand (transposed read)
  const float* inw1 = invn1w + bh*128;
  const float* inw2 = invn2w + bh*128;
  short* O = o34b + (long)(b*128 + cf)*16384;
  int t = threadIdx.x;
  int wave = t >> 6, lane = t & 63, lm = lane & 15, quad = lane >> 4;
  int m0 = (wave >> 1) << 6, n0 = (wave & 1) << 6;
  f32x4 acc[4][4];
  #pragma unroll
  for (int i = 0; i < 4; ++i)
    #pragma unroll
    for (int j = 0; j < 4; ++j) acc[i][j] = (f32x4){0.f,0.f,0.f,0.f};
  for (int g = 0; g < 4; ++g) {
    const short* Asrc = (g < 2) ? A0 : A1_;
    const short* Bsrc = (g < 2) ? B0 : B1_;
    long Bst = (g < 2) ? 2048 : 128;
    int k0 = (g & 1) << 6;
    __syncthreads();
    #pragma unroll
    for (int i = 0; i < 4; ++i) {
      int e = t + i*256;
      int row = e >> 3, off = (e & 7) << 3;
      *(float4*)(As + row*72 + off) = *(const float4*)(Asrc + (long)row*128 + k0 + off);
      *(float4*)(Bs + row*72 + off) = *(const float4*)(Bsrc + (long)row*Bst + k0 + off);
    }
    __syncthreads();
    #pragma unroll
    for (int ks = 0; ks < 64; ks += 32) {
      bf16x8 af[4], bfj[4];
      #pragma unroll
      for (int i = 0; i < 4; ++i)
        af[i] = *(const bf16x8*)(As + (m0 + i*16 + lm)*72 + ks + quad*8);
      #pragma unroll
      for (int j = 0; j < 4; ++j)
        bfj[j] = *(const bf16x8*)(Bs + (n0 + j*16 + lm)*72 + ks + quad*8);
      #pragma unroll
      for (int i = 0; i < 4; ++i)
        #pragma unroll
        for (int j = 0; j < 4; ++j)
          acc[i][j] = __builtin_amdgcn_mfma_f32_16x16x32_bf16(af[i], bfj[j], acc[i][j], 0, 0, 0);
    }
  }
  // q2 + q1 in register layout (row = m0+i*16+quad*4+r, col = n0+j*16+lm)
  float inwv[4];
  #pragma unroll
  for (int j = 0; j < 4; ++j) inwv[j] = inw1[n0 + j*16 + lm];
  #pragma unroll
  for (int i = 0; i < 4; ++i) {
    int row0 = m0 + i*16 + quad*4;
    f32x4 iv2 = *(const f32x4*)(inw2 + row0);
    #pragma unroll
    for (int j = 0; j < 4; ++j) {
      int col = n0 + j*16 + lm;
      f32x4 vq = *(const f32x4*)(o2p + (long)col*128 + row0);
      #pragma unroll
      for (int r = 0; r < 4; ++r)
        acc[i][j][r] += b2f(R[(long)(row0 + r)*2048 + col]) * inwv[j]
                      + vq[r] * iv2[r];
    }
  }
  // LDS-transposed store: 4 bf16 (8B) contiguous in w per thread
  __syncthreads();
  float* scr = (float*)As + wave*320;
  int co_l = lane >> 2, wq = (lane & 3) << 2;
  #pragma unroll
  for (int i = 0; i < 4; ++i) {
    #pragma unroll
    for (int j = 0; j < 4; ++j) {
      #pragma unroll
      for (int r = 0; r < 4; ++r)
        scr[(quad*4 + r)*20 + lm] = acc[i][j][r];
      f32x4 vv = *(f32x4*)(scr + co_l*20 + wq);
      int2 ov;
      ov.x = ((int)(unsigned short)f2b(vv[1])<<16) | (unsigned short)f2b(vv[0]);
      ov.y = ((int)(unsigned short)f2b(vv[3])<<16) | (unsigned short)f2b(vv[2]);
      *(int2*)(O + (long)(m0 + i*16 + co_l)*128 + n0 + j*16 + wq) = ov;
    }
  }
}

extern "C" void kernel_launch(void* const* d_in, const int* in_sizes, int n_in,
                              void* d_out, int out_size, void* d_ws, size_t ws_size,
                              hipStream_t stream)
{
  const float* x    = (const float*)d_in[0];
  const float* ln_w = (const float*)d_in[1];
  const float* ln_b = (const float*)d_in[2];
  const float* wd1  = (const float*)d_in[3];
  const float* gd1  = (const float*)d_in[4];
  const float* bd1  = (const float*)d_in[5];
  const float* wd2  = (const float*)d_in[6];
  const float* gd2  = (const float*)d_in[7];
  const float* bd2  = (const float*)d_in[8];
  const float* wd3  = (const float*)d_in[9];
  const float* gd3  = (const float*)d_in[10];
  const float* bd3  = (const float*)d_in[11];
  const float* w_out1 = (const float*)d_in[12];
  const float* w1 = (const float*)d_in[13]; const float* b1 = (const float*)d_in[14];
  const float* w2 = (const float*)d_in[15]; const float* b2 = (const float*)d_in[16];
  const float* w3 = (const float*)d_in[17]; const float* b3 = (const float*)d_in[18];
  const float* w4 = (const float*)d_in[19]; const float* b4 = (const float*)d_in[20];
  const float* w5 = (const float*)d_in[21]; const float* b5 = (const float*)d_in[22];
  const float* w6 = (const float*)d_in[23]; const float* b6 = (const float*)d_in[24];
  const float* w_out2 = (const float*)d_in[25];
  float* out = (float*)d_out;

  const long SLAB = 16777216L;
  float* buf0 = (float*)d_ws;            // xb -> sb -> x1 -> out1 -> o34b
  float* buf1 = buf0 + SLAB;             // y1 -> ab -> out1H|out2H -> ob
  float* buf2 = buf1 + SLAB;             // y2 -> out2
  float* dbuf = out;                     // y3 -> att(bf16) -> out1T|out2T -> final
  float* stats = buf2 + SLAB;            // 16 slices x 768
  float* invn1h = stats + NSLICE*768;    // 3 x 8192 accumulators (contiguous)
  float* invn1w = invn1h + 8192;
  float* invn2w = invn1w + 8192;
  short* wb2  = (short*)(invn2w + 8192);
  short* wb3  = wb2 + 147456;
  short* wb1  = wb3 + 147456;
  short* wbo1 = wb1 + 16384;
  short* wbo2 = wbo1 + 16384;
  short* A1b  = wbo2 + 16384;
  short* A2b  = A1b + 1048576;
  float* bnso = (float*)(A2b + 1048576); // 768 floats: BN scale/offset

  short* xb = (short*)buf0;
  short* sb = (short*)buf0;              // overwrites xb (dead after y-convs)
  short* attb = (short*)dbuf;            // bf16 att (overwrites y3, dead)
  short* ab = (short*)buf1;
  short* out1T = (short*)dbuf;
  short* out2T = out1T + 16777216;
  short* out1H = (short*)buf1;
  short* out2H = out1H + 16777216;
  short* o34b = (short*)buf0;            // bf16 o34 (out1 fp32 dead by then)
  short* ob = (short*)buf1;              // overwrites out1H (dead by then)

  k_zero<<<48, 256, 0, stream>>>(stats, NSLICE*768);
  k_zero<<<96, 256, 0, stream>>>(invn1h, 24576);   // all 3 norm accumulators
  k_reorg3b<<<576, 256, 0, stream>>>(wd2, wb2);
  k_reorg3b<<<576, 256, 0, stream>>>(wd3, wb3);
  k_cast<<<64, 256, 0, stream>>>(wd1, wb1);
  k_cast<<<64, 256, 0, stream>>>(w_out1, wbo1);
  k_cast<<<64, 256, 0, stream>>>(w_out2, wbo2);

  k_nhwc<<<16384, 256, 0, stream>>>(x, xb);
  k_mconv1<<<1024, 256, 0, stream>>>(xb, wb1, nullptr, buf1, 1, stats);      // y1 + stats0
  k_mconv<<<1024, 256, 0, stream>>>(xb, wb2, buf2, 3, 6, stats + 256);       // y2 + stats1
  k_mconv<<<1024, 256, 0, stream>>>(xb, wb3, dbuf, 3, 12, stats + 512);      // y3 + stats2
  k_bnfin<<<1, 128, 0, stream>>>(stats, gd1, bd1, gd2, bd2, gd3, bd3, bnso);
  k_bnapply<<<8192, 256, 0, stream>>>(buf1, buf2, dbuf, bnso, sb);   // sb bf16 NHWC (xb dead)
  k_mconv1<<<1024, 256, 0, stream>>>(sb, wbo1, x, buf2, 0, nullptr); // out2 (y2 dead)
  k_ln<<<512, 256, 0, stream>>>(x, ln_w, ln_b, buf0);                // x1 (sb dead)
  k_dw2<<<4096, 256, 0, stream>>>(buf0, w1,b1,w2,b2,w3,b3,w4,b4,w5,b5,w6,b6, attb); // att bf16 (y3 dead)
  k_nhwcb<<<16384, 256, 0, stream>>>(attb, ab);                      // ab (y1 dead)
  k_mconv1<<<1024, 256, 0, stream>>>(ab, wbo2, nullptr, buf0, 0, nullptr);   // out1 (x1 dead)
  k_thx<<<32768, 256, 0, stream>>>(buf0, buf2, out1T, out2T, out1H, out2H,
                                   invn1h, invn1w, invn2w);          // T/H + norm partials
  k_finw<<<96, 256, 0, stream>>>(invn1h);                            // finalize all 3 norms
  k_attnS_m<<<256, 256, 0, stream>>>(out1T, out2T, out1H,
                                     invn1h, invn1w, invn2w, A1b, A2b);
  k_o34f<<<1024, 256, 0, stream>>>(A1b, out1T, out1H, invn1w,
                                   out2H, A2b, buf2, invn2w, o34b);  // o34 bf16 = o3+o4+q2+q1
  k_nhwcb<<<16384, 256, 0, stream>>>(o34b, ob);                      // ob (out1H dead)
  k_mconv1<<<1024, 256, 0, stream>>>(ob, wbo2, x, out, 0, nullptr);  // final + x (T dead)
}

// Round 11
// 743.476 us; speedup vs baseline: 1.0294x; 1.0294x over previous
//
#include <hip/hip_runtime.h>

#define Bb 8
#define Cc 128
#define Hh 128
#define Ww 128
#define HW 16384
#define CHW (Cc*HW)
#define NHW (Bb*HW)
#define CH 16
#define EPS 1e-5f
#define NSLICE 16

typedef __attribute__((ext_vector_type(8))) short bf16x8;
typedef __attribute__((ext_vector_type(4))) float f32x4;

static __device__ __forceinline__ short f2b(float f) {
  unsigned u = __float_as_uint(f);
  unsigned lsb = (u >> 16) & 1;
  return (short)((u + 0x7fffu + lsb) >> 16);
}
static __device__ __forceinline__ float b2f(short s) {
  return __uint_as_float(((unsigned)(unsigned short)s) << 16);
}

// per-wave 16-lane butterfly + atomic stats update, SHARDED 16 ways by blockIdx
static __device__ __forceinline__ void stats_epilogue(
    float* __restrict__ statp, f32x4 acc[4][4], int co0, int quad, int lm)
{
  statp += (blockIdx.x & (NSLICE-1)) * 768;
  #pragma unroll
  for (int i = 0; i < 4; ++i) {
    f32x4 s = acc[i][0] + acc[i][1] + acc[i][2] + acc[i][3];
    f32x4 q = acc[i][0]*acc[i][0] + acc[i][1]*acc[i][1]
            + acc[i][2]*acc[i][2] + acc[i][3]*acc[i][3];
    #pragma unroll
    for (int m = 1; m < 16; m <<= 1) {
      #pragma unroll
      for (int e = 0; e < 4; ++e) {
        s[e] += __shfl_xor(s[e], m);
        q[e] += __shfl_xor(q[e], m);
      }
    }
    if (lm == 0) {
      int co = co0 + i*16 + quad*4;
      #pragma unroll
      for (int e = 0; e < 4; ++e) {
        atomicAdd(&statp[co + e], s[e]);
        atomicAdd(&statp[128 + co + e], q[e]);
      }
    }
  }
}

// ---------------- LayerNorm over channel dim ----------------
__global__ __launch_bounds__(256) void k_ln(const float* __restrict__ x,
    const float* __restrict__ g, const float* __restrict__ be,
    float* __restrict__ y)
{
  int p = blockIdx.x*256 + threadIdx.x;
  int b = p >> 14, hw = p & 16383;
  const float* xp = x + (long)b*CHW + hw;
  float s = 0.f, q = 0.f;
  for (int c = 0; c < Cc; ++c) { float v = xp[c*HW]; s += v; q += v*v; }
  float mu = s * (1.f/Cc);
  float var = q * (1.f/Cc) - mu*mu;
  float rstd = rsqrtf(var + EPS);
  float* yp = y + (long)b*CHW + hw;
  for (int c = 0; c < Cc; ++c) {
    float v = xp[c*HW];
    yp[c*HW] = (v - mu) * rstd * g[c] + be[c];
  }
}

// ---------------- 3x3 weight: [co][ci][tap] fp32 -> [tap][co][ci] bf16 ----------------
__global__ __launch_bounds__(256) void k_reorg3b(const float* __restrict__ Wt, short* __restrict__ out)
{
  int idx = blockIdx.x*256 + threadIdx.x;
  int tap = idx >> 14, r = idx & 16383;
  out[idx] = f2b(Wt[r*9 + tap]);
}

__global__ __launch_bounds__(256) void k_cast(const float* __restrict__ in, short* __restrict__ out)
{
  int i = blockIdx.x*256 + threadIdx.x;
  out[i] = f2b(in[i]);
}

__global__ __launch_bounds__(256) void k_zero(float* p, int n)
{
  int i = blockIdx.x*256 + threadIdx.x;
  if (i < n) p[i] = 0.f;
}

// ---------------- NCHW fp32 -> NHWC bf16 ----------------
__global__ __launch_bounds__(256) void k_nhwc(const float* __restrict__ in, short* __restrict__ out)
{
  __shared__ float Ls[32][33];
  int bid = blockIdx.x;
  int hwt = bid & 511, c4 = (bid>>9)&3, b = bid>>11;
  int hw0 = hwt << 5, c0 = c4 << 5;
  int t = threadIdx.x;
  int hl = t & 31, cl = t >> 5;
  const float* p = in + (long)b*CHW + hw0;
  for (int r = cl; r < 32; r += 8)
    Ls[r][hl] = p[(long)(c0+r)*HW + hl];
  __syncthreads();
  short* q = out + ((long)b*HW + hw0)*Cc + c0;
  int ccl = t & 31, hl0 = t >> 5;
  for (int r = hl0; r < 32; r += 8)
    q[(long)r*Cc + ccl] = f2b(Ls[ccl][r]);
}

// ---------------- NCHW bf16 -> NHWC bf16 (no re-round) ----------------
__global__ __launch_bounds__(256) void k_nhwcb(const short* __restrict__ in, short* __restrict__ out)
{
  __shared__ short Ls[32][34];
  int bid = blockIdx.x;
  int hwt = bid & 511, c4 = (bid>>9)&3, b = bid>>11;
  int hw0 = hwt << 5, c0 = c4 << 5;
  int t = threadIdx.x;
  int hl = t & 31, cl = t >> 5;
  const short* p = in + (long)b*CHW + hw0;
  for (int r = cl; r < 32; r += 8)
    Ls[r][hl] = p[(long)(c0+r)*HW + hl];
  __syncthreads();
  short* q = out + ((long)b*HW + hw0)*Cc + c0;
  int ccl = t & 31, hl0 = t >> 5;
  for (int r = hl0; r < 32; r += 8)
    q[(long)r*Cc + ccl] = Ls[ccl][r];
}

// ---------------- MFMA conv, dilated 3x3, full-K LDS tiles, NHWC fp32 output ----
__global__ __launch_bounds__(256,2) void k_mconv(const short* __restrict__ X,
    const short* __restrict__ W, float* __restrict__ Y, int k3, int dil,
    float* __restrict__ statp)
{
  __shared__ short Ws[128*136];
  __shared__ short Xs[152*136];
  int b = blockIdx.x >> 7, h = blockIdx.x & 127;
  int t = threadIdx.x;
  int wave = t >> 6, lane = t & 63;
  int co0 = (wave >> 1) << 6, sp0 = (wave & 1) << 6;
  int lm = lane & 15, quad = lane >> 4;
  f32x4 acc[4][4];
  #pragma unroll
  for (int i = 0; i < 4; ++i)
    #pragma unroll
    for (int j = 0; j < 4; ++j) acc[i][j] = (f32x4){0.f,0.f,0.f,0.f};
  int half = k3 >> 1;

  {
    f32x4 z = {0.f,0.f,0.f,0.f};
    for (int i = t; i < 408; i += 256) {        // 24 halo rows x 17 f32x4
      int r = i / 17, o = i - r*17;
      int row = r < 12 ? r : r + 128;
      *(f32x4*)(Xs + row*136 + o*8) = z;
    }
  }

  for (int kh = 0; kh < k3; ++kh) {
    int hs = h + (kh - half)*dil;
    if ((unsigned)hs >= (unsigned)Hh) continue;
    __syncthreads();
    {
      const short* xr = X + ((long)(b*Hh + hs)*Ww)*Cc;
      #pragma unroll
      for (int it = 0; it < 8; ++it) {
        int i = t + it*256;
        int row = i >> 4, off = (i & 15) << 3;
        *(f32x4*)(Xs + (12 + row)*136 + off) = *(const f32x4*)(xr + (long)row*Cc + off);
      }
    }
    for (int kw = 0; kw < k3; ++kw) {
      int dw = (kw - half)*dil;
      if (kw) __syncthreads();
      {
        const short* wt = W + (kh*k3 + kw)*16384;
        #pragma unroll
        for (int it = 0; it < 8; ++it) {
          int i = t + it*256;
          int row = i >> 4, off = (i & 15) << 3;
          *(f32x4*)(Ws + row*136 + off) = *(const f32x4*)(wt + (long)row*128 + off);
        }
      }
      __syncthreads();
      int xrow0 = 12 + dw + sp0;
      for (int kc = 0; kc < 4; ++kc) {
        int k0 = kc << 5;
        bf16x8 af[4], bfr[4];
        #pragma unroll
        for (int i = 0; i < 4; ++i)
          af[i] = *(const bf16x8*)(Ws + (co0 + i*16 + lm)*136 + k0 + quad*8);
        #pragma unroll
        for (int j = 0; j < 4; ++j)
          bfr[j] = *(const bf16x8*)(Xs + (xrow0 + j*16 + lm)*136 + k0 + quad*8);
        #pragma unroll
        for (int i = 0; i < 4; ++i)
          #pragma unroll
          for (int j = 0; j < 4; ++j)
            acc[i][j] = __builtin_amdgcn_mfma_f32_16x16x32_bf16(af[i], bfr[j], acc[i][j], 0, 0, 0);
      }
    }
  }
  float* yb = Y + ((long)(b*Hh + h)*Ww)*Cc;
  #pragma unroll
  for (int i = 0; i < 4; ++i) {
    int co = co0 + i*16 + quad*4;
    #pragma unroll
    for (int j = 0; j < 4; ++j) {
      int wc = sp0 + j*16 + lm;
      *(f32x4*)(yb + (long)wc*Cc + co) = acc[i][j];
    }
  }
  if (statp) stats_epilogue(statp, acc, co0, quad, lm);
}

// ---------------- MFMA 1x1 conv: weights in LDS, X fragments direct from global ----
__global__ __launch_bounds__(256,4) void k_mconv1(const short* __restrict__ X,
    const short* __restrict__ W, const float* __restrict__ res,
    float* __restrict__ Y, int nhwc, float* __restrict__ statp)
{
  __shared__ short Ws[128*136];
  int b = blockIdx.x >> 7, h = blockIdx.x & 127;
  int t = threadIdx.x;
  int wave = t >> 6, lane = t & 63;
  int co0 = (wave >> 1) << 6, sp0 = (wave & 1) << 6;
  int lm = lane & 15, quad = lane >> 4;
  #pragma unroll
  for (int it = 0; it < 8; ++it) {
    int i = t + it*256;
    int row = i >> 4, off = (i & 15) << 3;
    *(f32x4*)(Ws + row*136 + off) = *(const f32x4*)(W + (long)row*128 + off);
  }
  f32x4 acc[4][4];
  #pragma unroll
  for (int i = 0; i < 4; ++i)
    #pragma unroll
    for (int j = 0; j < 4; ++j) acc[i][j] = (f32x4){0.f,0.f,0.f,0.f};
  const short* xr = X + ((long)(b*Hh + h)*Ww)*Cc;
  __syncthreads();
  #pragma unroll
  for (int kc = 0; kc < 4; ++kc) {
    int k0 = kc << 5;
    bf16x8 af[4], bfr[4];
    #pragma unroll
    for (int j = 0; j < 4; ++j)
      bfr[j] = *(const bf16x8*)(xr + (long)(sp0 + j*16 + lm)*Cc + k0 + quad*8);
    #pragma unroll
    for (int i = 0; i < 4; ++i)
      af[i] = *(const bf16x8*)(Ws + (co0 + i*16 + lm)*136 + k0 + quad*8);
    #pragma unroll
    for (int i = 0; i < 4; ++i)
      #pragma unroll
      for (int j = 0; j < 4; ++j)
        acc[i][j] = __builtin_amdgcn_mfma_f32_16x16x32_bf16(af[i], bfr[j], acc[i][j], 0, 0, 0);
  }
  if (nhwc) {
    float* yb = Y + ((long)(b*Hh + h)*Ww)*Cc;
    #pragma unroll
    for (int i = 0; i < 4; ++i) {
      int co = co0 + i*16 + quad*4;
      #pragma unroll
      for (int j = 0; j < 4; ++j) {
        int wc = sp0 + j*16 + lm;
        *(f32x4*)(yb + (long)wc*Cc + co) = acc[i][j];
      }
    }
    if (statp) stats_epilogue(statp, acc, co0, quad, lm);
  } else {
    __syncthreads();                       // all waves done reading Ws
    float* scr = (float*)Ws + wave*320;    // 16 rows x stride 20 f32, wave-private
    int co_l = lane >> 2, wq = (lane & 3) << 2;
    #pragma unroll
    for (int i = 0; i < 4; ++i) {
      #pragma unroll
      for (int j = 0; j < 4; ++j) {
        #pragma unroll
        for (int r = 0; r < 4; ++r)
          scr[(quad*4 + r)*20 + lm] = acc[i][j][r];
        f32x4 vv = *(f32x4*)(scr + co_l*20 + wq);
        int co = co0 + i*16 + co_l;
        int wc = sp0 + j*16 + wq;
        long idx = ((long)(b*Cc + co)*Hh + h)*Ww + wc;
        if (res) vv += *(const f32x4*)(res + idx);
        *(f32x4*)(Y + idx) = vv;
      }
    }
  }
}

// ---------------- BN finalize: sum 16 slices -> per-channel scale/offset ----------------
__global__ __launch_bounds__(128) void k_bnfin(const float* __restrict__ stats,
    const float* __restrict__ g1, const float* __restrict__ be1,
    const float* __restrict__ g2, const float* __restrict__ be2,
    const float* __restrict__ g3, const float* __restrict__ be3,
    float* __restrict__ so)
{
  int c = threadIdx.x;
  const float inv = 1.f/(float)NHW;
  const float* gs[3] = {g1, g2, g3};
  const float* bs[3] = {be1, be2, be3};
  #pragma unroll
  for (int tsel = 0; tsel < 3; ++tsel) {
    float su = 0.f, qu = 0.f;
    for (int sl = 0; sl < NSLICE; ++sl) {
      su += stats[sl*768 + tsel*256 + c];
      qu += stats[sl*768 + tsel*256 + 128 + c];
    }
    float mu = su*inv;
    float var = qu*inv - mu*mu;
    float s = rsqrtf(var + EPS)*gs[tsel][c];
    so[tsel*256 + c] = s;
    so[tsel*256 + 128 + c] = bs[tsel][c] - mu*s;
  }
}

// ---------------- BN apply + relu, sum three branches (NHWC in) -> sb bf16 NHWC ----
__global__ __launch_bounds__(256) void k_bnapply(const float* __restrict__ y1,
    const float* __restrict__ y2, const float* __restrict__ y3,
    const float* __restrict__ so, short* __restrict__ sb)
{
  long e = ((long)blockIdx.x*256 + threadIdx.x) * 8;
  int c = (int)(e & 127);
  f32x4 s1a = *(const f32x4*)(so + c),        s1b = *(const f32x4*)(so + c + 4);
  f32x4 o1a = *(const f32x4*)(so + 128 + c),  o1b = *(const f32x4*)(so + 132 + c);
  f32x4 s2a = *(const f32x4*)(so + 256 + c),  s2b = *(const f32x4*)(so + 260 + c);
  f32x4 o2a = *(const f32x4*)(so + 384 + c),  o2b = *(const f32x4*)(so + 388 + c);
  f32x4 s3a = *(const f32x4*)(so + 512 + c),  s3b = *(const f32x4*)(so + 516 + c);
  f32x4 o3a = *(const f32x4*)(so + 640 + c),  o3b = *(const f32x4*)(so + 644 + c);
  f32x4 v1a = *(const f32x4*)(y1 + e), v1b = *(const f32x4*)(y1 + e + 4);
  f32x4 v2a = *(const f32x4*)(y2 + e), v2b = *(const f32x4*)(y2 + e + 4);
  f32x4 v3a = *(const f32x4*)(y3 + e), v3b = *(const f32x4*)(y3 + e + 4);
  float r[8];
  #pragma unroll
  for (int k = 0; k < 4; ++k) {
    r[k] = fmaxf(fmaf(v1a[k], s1a[k], o1a[k]), 0.f)
         + fmaxf(fmaf(v2a[k], s2a[k], o2a[k]), 0.f)
         + fmaxf(fmaf(v3a[k], s3a[k], o3a[k]), 0.f);
    r[4+k] = fmaxf(fmaf(v1b[k], s1b[k], o1b[k]), 0.f)
           + fmaxf(fmaf(v2b[k], s2b[k], o2b[k]), 0.f)
           + fmaxf(fmaf(v3b[k], s3b[k], o3b[k]), 0.f);
  }
  int4 o;
  o.x = ((int)(unsigned short)f2b(r[1])<<16) | (unsigned short)f2b(r[0]);
  o.y = ((int)(unsigned short)f2b(r[3])<<16) | (unsigned short)f2b(r[2]);
  o.z = ((int)(unsigned short)f2b(r[5])<<16) | (unsigned short)f2b(r[4]);
  o.w = ((int)(unsigned short)f2b(r[7])<<16) | (unsigned short)f2b(r[6]);
  *(int4*)(sb + e) = o;
}

// ---------------- six depthwise branches summed, LDS-tiled stencil, bf16 out ----
__global__ __launch_bounds__(256) void k_dw2(const float* __restrict__ X,
    const float* __restrict__ w1, const float* __restrict__ b1,
    const float* __restrict__ w2, const float* __restrict__ b2,
    const float* __restrict__ w3, const float* __restrict__ b3,
    const float* __restrict__ w4, const float* __restrict__ b4,
    const float* __restrict__ w5, const float* __restrict__ b5,
    const float* __restrict__ w6, const float* __restrict__ b6,
    short* __restrict__ Y)
{
  __shared__ float Ls[38][136];
  int bid = blockIdx.x;
  int tile = bid & 3, plane = bid >> 2;
  int c = plane & 127;
  int h0 = tile << 5;
  int t = threadIdx.x;

  float hcoef[7], vcoef[7], k9[9];
  #pragma unroll
  for (int d = 0; d < 7; ++d) { hcoef[d] = w5[c*7+d]; vcoef[d] = w6[c*7+d]; }
  #pragma unroll
  for (int d = 1; d < 6; ++d) { hcoef[d] += w1[c*5+d-1]; vcoef[d] += w2[c*5+d-1]; }
  hcoef[3] += w3[c];
  #pragma unroll
  for (int k = 0; k < 9; ++k) k9[k] = w4[c*9+k];
  float bias = b1[c]+b2[c]+b3[c]+b4[c]+b5[c]+b6[c];

  const float* xp = X + (long)plane*HW;

  f32x4* lz = (f32x4*)&Ls[0][0];
  for (int i = t; i < 1292; i += 256) lz[i] = (f32x4){0.f,0.f,0.f,0.f};
  __syncthreads();
  for (int i = t; i < 1216; i += 256) {
    int r = i >> 5, cg = (i & 31) << 2;
    int h = h0 - 3 + r;
    if ((unsigned)h < 128u)
      *(f32x4*)&Ls[r][4 + cg] = *(const f32x4*)(xp + h*128 + cg);
  }
  __syncthreads();

  int g = t & 31, rs = t >> 5;
  int w0 = g << 2;
  short* Yp = Y + (long)plane*HW;

  for (int ro = 0; ro < 4; ++ro) {
    int lr = rs + (ro << 3);
    int R = lr + 3;
    f32x4 a0 = *(const f32x4*)&Ls[R][w0];
    f32x4 a1 = *(const f32x4*)&Ls[R][w0+4];
    f32x4 a2 = *(const f32x4*)&Ls[R][w0+8];
    f32x4 u0 = *(const f32x4*)&Ls[R-1][w0];
    f32x4 u1 = *(const f32x4*)&Ls[R-1][w0+4];
    f32x4 u2 = *(const f32x4*)&Ls[R-1][w0+8];
    f32x4 d0 = *(const f32x4*)&Ls[R+1][w0];
    f32x4 d1 = *(const f32x4*)&Ls[R+1][w0+4];
    f32x4 d2 = *(const f32x4*)&Ls[R+1][w0+8];
    f32x4 v3u = *(const f32x4*)&Ls[R-3][w0+4];
    f32x4 v2u = *(const f32x4*)&Ls[R-2][w0+4];
    f32x4 v2d = *(const f32x4*)&Ls[R+2][w0+4];
    f32x4 v3d = *(const f32x4*)&Ls[R+3][w0+4];

    float cr[12], ur[12], dr[12];
    #pragma unroll
    for (int k = 0; k < 4; ++k) {
      cr[k] = a0[k]; cr[4+k] = a1[k]; cr[8+k] = a2[k];
      ur[k] = u0[k]; ur[4+k] = u1[k]; ur[8+k] = u2[k];
      dr[k] = d0[k]; dr[4+k] = d1[k]; dr[8+k] = d2[k];
    }

    float o[4];
    #pragma unroll
    for (int j = 0; j < 4; ++j) {
      float acc = bias;
      #pragma unroll
      for (int d = 0; d < 7; ++d) acc = fmaf(hcoef[d], cr[j+d+1], acc);
      acc = fmaf(vcoef[0], v3u[j], acc);
      acc = fmaf(vcoef[1], v2u[j], acc);
      acc = fmaf(vcoef[2], ur[j+4], acc);
      acc = fmaf(vcoef[3], cr[j+4], acc);
      acc = fmaf(vcoef[4], dr[j+4], acc);
      acc = fmaf(vcoef[5], v2d[j], acc);
      acc = fmaf(vcoef[6], v3d[j], acc);
      #pragma unroll
      for (int kw = 0; kw < 3; ++kw) {
        acc = fmaf(k9[kw],   ur[j+3+kw], acc);
        acc = fmaf(k9[3+kw], cr[j+3+kw], acc);
        acc = fmaf(k9[6+kw], dr[j+3+kw], acc);
      }
      o[j] = acc;
    }
    int2 ov;
    ov.x = ((int)(unsigned short)f2b(o[1])<<16) | (unsigned short)f2b(o[0]);
    ov.y = ((int)(unsigned short)f2b(o[3])<<16) | (unsigned short)f2b(o[2]);
    *(int2*)(Yp + (h0 + lr)*128 + w0) = ov;
  }
}

// ---------------- finalize: acc -> 1/max(sqrt(acc),1e-12), in place ----------------
__global__ __launch_bounds__(256) void k_finw(float* __restrict__ p)
{
  int i = blockIdx.x*256 + threadIdx.x;
  float v = p[i];
  p[i] = 1.f/fmaxf(sqrtf(v), 1e-12f);
}

// ---------------- fused transpose+cast+NORM: per 32x32 tile of out1/out2 produce
// out?T (transposed bf16) AND out?H; ALSO accumulate row/col square-sums into
// the norm accumulators (invn1h for out1 rows; invn1w/invn2w for cols).
__global__ __launch_bounds__(256) void k_thx(const float* __restrict__ out1,
    const float* __restrict__ out2,
    short* __restrict__ out1T, short* __restrict__ out2T,
    short* __restrict__ out1H, short* __restrict__ out2H,
    float* __restrict__ n1h, float* __restrict__ n1w, float* __restrict__ n2w)
{
  __shared__ float Ls[32][33];
  int bid = blockIdx.x;
  int wt = bid&3, ht=(bid>>2)&3, c=(bid>>4)&127, b=(bid>>11)&7, src=bid>>14;
  const float* in = (src ? out2 : out1) + (long)(b*128+c)*16384;
  long tbase = ((long)(b*8 + (c>>4))*128)*2048 + (c&15)*128;
  short* pT = (src ? out2T : out1T) + tbase;
  short* pH; long hstr;
  if (src) { pH = out2H + (long)(b*128+c)*16384; hstr = 128; }
  else     { pH = out1H + tbase;                 hstr = 2048; }
  int h0 = ht*32, w0 = wt*32;
  int t = threadIdx.x, li = t&31, r0 = t>>5;
  for (int r = r0; r < 32; r += 8)
    Ls[r][li] = in[(h0+r)*128 + w0 + li];
  __syncthreads();
  int bhbase = (b*8 + (c>>4))*128;
  if (t < 32) {
    if (!src) {
      float s = 0.f;
      for (int k = 0; k < 32; ++k) { float v = Ls[t][k]; s += v*v; }
      atomicAdd(&n1h[bhbase + h0 + t], s);
    }
  } else if (t < 64) {
    int w = t - 32;
    float s = 0.f;
    for (int k = 0; k < 32; ++k) { float v = Ls[k][w]; s += v*v; }
    atomicAdd((src ? n2w : n1w) + bhbase + w0 + w, s);
  }
  for (int r = r0; r < 32; r += 8) {
    pT[(long)(w0+r)*2048 + h0 + li] = f2b(Ls[li][r]);
    pH[(long)(h0+r)*hstr + w0 + li] = f2b(Ls[r][li]);
  }
}

// ---------------- MFMA attention S + softmax -> A1/A2 (bf16 row-major) ----------------
// grid 128 = type(2) x bh(64). Block: 128 rows x 128 cols, K=2048.
// 4 waves x (32 rows x 128 cols) so each softmax row lives in one wave.
__global__ __launch_bounds__(256) void k_attnS_m(
    const short* __restrict__ out1T, const short* __restrict__ out2T,
    const short* __restrict__ out1H,
    const float* __restrict__ invn1h, const float* __restrict__ invn1w,
    const float* __restrict__ invn2w,
    short* __restrict__ A1b, short* __restrict__ A2b)
{
  __shared__ short As[128*72];
  __shared__ short Bs[128*72];
  int bid = blockIdx.x;
  int type = bid >> 6, bh = bid & 63;
  const short* Aop = (type ? out1T : out2T) + (long)bh*262144;
  const short* Bop = (type ? out2T : out1H) + (long)bh*262144;
  const float* invrow = (type ? invn1w : invn2w) + bh*128;
  const float* invcol = (type ? invn2w : invn1h) + bh*128;
  short* Aout = (type ? A2b : A1b) + (long)bh*16384;
  int t = threadIdx.x;
  int wave = t >> 6, lane = t & 63, lm = lane & 15, quad = lane >> 4;
  int m0 = wave << 5;
  f32x4 acc[2][8];
  #pragma unroll
  for (int i = 0; i < 2; ++i)
    #pragma unroll
    for (int j = 0; j < 8; ++j) acc[i][j] = (f32x4){0.f,0.f,0.f,0.f};
  for (int kc = 0; kc < 32; ++kc) {
    int k0 = kc << 6;
    __syncthreads();
    #pragma unroll
    for (int i = 0; i < 4; ++i) {
      int e = t + i*256;
      int row = e >> 3, off = (e & 7) << 3;
      *(float4*)(As + row*72 + off) = *(const float4*)(Aop + (long)row*2048 + k0 + off);
      *(float4*)(Bs + row*72 + off) = *(const float4*)(Bop + (long)row*2048 + k0 + off);
    }
    __syncthreads();
    #pragma unroll
    for (int ks = 0; ks < 64; ks += 32) {
      bf16x8 af[2], bfj[8];
      #pragma unroll
      for (int i = 0; i < 2; ++i)
        af[i] = *(const bf16x8*)(As + (m0 + i*16 + lm)*72 + ks + quad*8);
      #pragma unroll
      for (int j = 0; j < 8; ++j)
        bfj[j] = *(const bf16x8*)(Bs + (j*16 + lm)*72 + ks + quad*8);
      #pragma unroll
      for (int i = 0; i < 2; ++i)
        #pragma unroll
        for (int j = 0; j < 8; ++j)
          acc[i][j] = __builtin_amdgcn_mfma_f32_16x16x32_bf16(af[i], bfj[j], acc[i][j], 0, 0, 0);
    }
  }
  float colv[8];
  #pragma unroll
  for (int j = 0; j < 8; ++j) colv[j] = invcol[j*16 + lm];
  #pragma unroll
  for (int i = 0; i < 2; ++i) {
    #pragma unroll
    for (int r = 0; r < 4; ++r) {
      int row = m0 + i*16 + quad*4 + r;
      float rs = invrow[row];
      float sv[8];
      float mx = -1e30f;
      #pragma unroll
      for (int j = 0; j < 8; ++j) {
        sv[j] = acc[i][j][r] * rs * colv[j];
        mx = fmaxf(mx, sv[j]);
      }
      mx = fmaxf(mx, __shfl_xor(mx, 1));
      mx = fmaxf(mx, __shfl_xor(mx, 2));
      mx = fmaxf(mx, __shfl_xor(mx, 4));
      mx = fmaxf(mx, __shfl_xor(mx, 8));
      float sum = 0.f;
      #pragma unroll
      for (int j = 0; j < 8; ++j) { sv[j] = __expf(sv[j] - mx); sum += sv[j]; }
      sum += __shfl_xor(sum, 1);
      sum += __shfl_xor(sum, 2);
      sum += __shfl_xor(sum, 4);
      sum += __shfl_xor(sum, 8);
      float inv = 1.f/sum;
      #pragma unroll
      for (int j = 0; j < 8; ++j)
        Aout[row*128 + j*16 + lm] = f2b(sv[j]*inv);
    }
  }
}

// ---------------- fused o34: o3 + o4 + q2 + q1, single bf16 write ----------------
__global__ __launch_bounds__(256) void k_o34f(
    const short* __restrict__ A1b, const short* __restrict__ out1T,
    const short* __restrict__ out1H, const float* __restrict__ invn1w,
    const short* __restrict__ out2H, const short* __restrict__ A2b,
    const float* __restrict__ out2, const float* __restrict__ invn2w,
    short* __restrict__ o34b)
{
  __shared__ short As[128*72];
  __shared__ short Bs[128*72];
  int bid = blockIdx.x;
  int cf = bid & 127, b = bid >> 7;
  int hd = cf >> 4, c = cf & 15;
  int bh = b*8 + hd;
  const short* A0 = A1b + (long)bh*16384;              // [h][k] stride 128
  const short* B0 = out1T + (long)bh*262144 + c*128;   // [w][k] stride 2048
  const short* A1_ = out2H + (long)(b*128 + cf)*16384; // [h][k] stride 128
  const short* B1_ = A2b + (long)bh*16384;             // [w][k] stride 128
  const short* R = out1H + (long)bh*262144 + c*128;    // q2 operand, stride 2048
  const float* o2p = out2 + (long)(b*128 + cf)*16384;  // q1 operand (transposed read)
  const float* inw1 = invn1w + bh*128;
  const float* inw2 = invn2w + bh*128;
  short* O = o34b + (long)(b*128 + cf)*16384;
  int t = threadIdx.x;
  int wave = t >> 6, lane = t & 63, lm = lane & 15, quad = lane >> 4;
  int m0 = (wave >> 1) << 6, n0 = (wave & 1) << 6;
  f32x4 acc[4][4];
  #pragma unroll
  for (int i = 0; i < 4; ++i)
    #pragma unroll
    for (int j = 0; j < 4; ++j) acc[i][j] = (f32x4){0.f,0.f,0.f,0.f};
  for (int g = 0; g < 4; ++g) {
    const short* Asrc = (g < 2) ? A0 : A1_;
    const short* Bsrc = (g < 2) ? B0 : B1_;
    long Bst = (g < 2) ? 2048 : 128;
    int k0 = (g & 1) << 6;
    __syncthreads();
    #pragma unroll
    for (int i = 0; i < 4; ++i) {
      int e = t + i*256;
      int row = e >> 3, off = (e & 7) << 3;
      *(float4*)(As + row*72 + off) = *(const float4*)(Asrc + (long)row*128 + k0 + off);
      *(float4*)(Bs + row*72 + off) = *(const float4*)(Bsrc + (long)row*Bst + k0 + off);
    }
    __syncthreads();
    #pragma unroll
    for (int ks = 0; ks < 64; ks += 32) {
      bf16x8 af[4], bfj[4];
      #pragma unroll
      for (int i = 0; i < 4; ++i)
        af[i] = *(const bf16x8*)(As + (m0 + i*16 + lm)*72 + ks + quad*8);
      #pragma unroll
      for (int j = 0; j < 4; ++j)
        bfj[j] = *(const bf16x8*)(Bs + (n0 + j*16 + lm)*72 + ks + quad*8);
      #pragma unroll
      for (int i = 0; i < 4; ++i)
        #pragma unroll
        for (int j = 0; j < 4; ++j)
          acc[i][j] = __builtin_amdgcn_mfma_f32_16x16x32_bf16(af[i], bfj[j], acc[i][j], 0, 0, 0);
    }
  }
  // q2 + q1 in register layout (row = m0+i*16+quad*4+r, col = n0+j*16+lm)
  float inwv[4];
  #pragma unroll
  for (int j = 0; j < 4; ++j) inwv[j] = inw1[n0 + j*16 + lm];
  #pragma unroll
  for (int i = 0; i < 4; ++i) {
    int row0 = m0 + i*16 + quad*4;
    f32x4 iv2 = *(const f32x4*)(inw2 + row0);
    #pragma unroll
    for (int j = 0; j < 4; ++j) {
      int col = n0 + j*16 + lm;
      f32x4 vq = *(const f32x4*)(o2p + (long)col*128 + row0);
      #pragma unroll
      for (int r = 0; r < 4; ++r)
        acc[i][j][r] += b2f(R[(long)(row0 + r)*2048 + col]) * inwv[j]
                      + vq[r] * iv2[r];
    }
  }
  // LDS-transposed store: 4 bf16 (8B) contiguous in w per thread
  __syncthreads();
  float* scr = (float*)As + wave*320;
  int co_l = lane >> 2, wq = (lane & 3) << 2;
  #pragma unroll
  for (int i = 0; i < 4; ++i) {
    #pragma unroll
    for (int j = 0; j < 4; ++j) {
      #pragma unroll
      for (int r = 0; r < 4; ++r)
        scr[(quad*4 + r)*20 + lm] = acc[i][j][r];
      f32x4 vv = *(f32x4*)(scr + co_l*20 + wq);
      int2 ov;
      ov.x = ((int)(unsigned short)f2b(vv[1])<<16) | (unsigned short)f2b(vv[0]);
      ov.y = ((int)(unsigned short)f2b(vv[3])<<16) | (unsigned short)f2b(vv[2]);
      *(int2*)(O + (long)(m0 + i*16 + co_l)*128 + n0 + j*16 + wq) = ov;
    }
  }
}

extern "C" void kernel_launch(void* const* d_in, const int* in_sizes, int n_in,
                              void* d_out, int out_size, void* d_ws, size_t ws_size,
                              hipStream_t stream)
{
  const float* x    = (const float*)d_in[0];
  const float* ln_w = (const float*)d_in[1];
  const float* ln_b = (const float*)d_in[2];
  const float* wd1  = (const float*)d_in[3];
  const float* gd1  = (const float*)d_in[4];
  const float* bd1  = (const float*)d_in[5];
  const float* wd2  = (const float*)d_in[6];
  const float* gd2  = (const float*)d_in[7];
  const float* bd2  = (const float*)d_in[8];
  const float* wd3  = (const float*)d_in[9];
  const float* gd3  = (const float*)d_in[10];
  const float* bd3  = (const float*)d_in[11];
  const float* w_out1 = (const float*)d_in[12];
  const float* w1 = (const float*)d_in[13]; const float* b1 = (const float*)d_in[14];
  const float* w2 = (const float*)d_in[15]; const float* b2 = (const float*)d_in[16];
  const float* w3 = (const float*)d_in[17]; const float* b3 = (const float*)d_in[18];
  const float* w4 = (const float*)d_in[19]; const float* b4 = (const float*)d_in[20];
  const float* w5 = (const float*)d_in[21]; const float* b5 = (const float*)d_in[22];
  const float* w6 = (const float*)d_in[23]; const float* b6 = (const float*)d_in[24];
  const float* w_out2 = (const float*)d_in[25];
  float* out = (float*)d_out;

  const long SLAB = 16777216L;
  float* buf0 = (float*)d_ws;            // xb -> sb -> x1 -> out1 -> o34b
  float* buf1 = buf0 + SLAB;             // y1 -> ab -> out1H|out2H -> ob
  float* buf2 = buf1 + SLAB;             // y2 -> out2
  float* dbuf = out;                     // y3 -> att(bf16) -> out1T|out2T -> final
  float* stats = buf2 + SLAB;            // 16 slices x 768
  float* invn1h = stats + NSLICE*768;    // 3 x 8192 accumulators (contiguous)
  float* invn1w = invn1h + 8192;
  float* invn2w = invn1w + 8192;
  short* wb2  = (short*)(invn2w + 8192);
  short* wb3  = wb2 + 147456;
  short* wb1  = wb3 + 147456;
  short* wbo1 = wb1 + 16384;
  short* wbo2 = wbo1 + 16384;
  short* A1b  = wbo2 + 16384;
  short* A2b  = A1b + 1048576;
  float* bnso = (float*)(A2b + 1048576); // 768 floats: BN scale/offset

  short* xb = (short*)buf0;
  short* sb = (short*)buf0;              // overwrites xb (dead after y-convs)
  short* attb = (short*)dbuf;            // bf16 att (overwrites y3, dead)
  short* ab = (short*)buf1;
  short* out1T = (short*)dbuf;
  short* out2T = out1T + 16777216;
  short* out1H = (short*)buf1;
  short* out2H = out1H + 16777216;
  short* o34b = (short*)buf0;            // bf16 o34 (out1 fp32 dead by then)
  short* ob = (short*)buf1;              // overwrites out1H (dead by then)

  k_zero<<<48, 256, 0, stream>>>(stats, NSLICE*768);
  k_zero<<<96, 256, 0, stream>>>(invn1h, 24576);   // all 3 norm accumulators
  k_reorg3b<<<576, 256, 0, stream>>>(wd2, wb2);
  k_reorg3b<<<576, 256, 0, stream>>>(wd3, wb3);
  k_cast<<<64, 256, 0, stream>>>(wd1, wb1);
  k_cast<<<64, 256, 0, stream>>>(w_out1, wbo1);
  k_cast<<<64, 256, 0, stream>>>(w_out2, wbo2);

  k_nhwc<<<16384, 256, 0, stream>>>(x, xb);
  k_mconv1<<<1024, 256, 0, stream>>>(xb, wb1, nullptr, buf1, 1, stats);      // y1 + stats0
  k_mconv<<<1024, 256, 0, stream>>>(xb, wb2, buf2, 3, 6, stats + 256);       // y2 + stats1
  k_mconv<<<1024, 256, 0, stream>>>(xb, wb3, dbuf, 3, 12, stats + 512);      // y3 + stats2
  k_bnfin<<<1, 128, 0, stream>>>(stats, gd1, bd1, gd2, bd2, gd3, bd3, bnso);
  k_bnapply<<<8192, 256, 0, stream>>>(buf1, buf2, dbuf, bnso, sb);   // sb bf16 NHWC (xb dead)
  k_mconv1<<<1024, 256, 0, stream>>>(sb, wbo1, x, buf2, 0, nullptr); // out2 (y2 dead)
  k_ln<<<512, 256, 0, stream>>>(x, ln_w, ln_b, buf0);                // x1 (sb dead)
  k_dw2<<<4096, 256, 0, stream>>>(buf0, w1,b1,w2,b2,w3,b3,w4,b4,w5,b5,w6,b6, attb); // att bf16 (y3 dead)
  k_nhwcb<<<16384, 256, 0, stream>>>(attb, ab);                      // ab (y1 dead)
  k_mconv1<<<1024, 256, 0, stream>>>(ab, wbo2, nullptr, buf0, 0, nullptr);   // out1 (x1 dead)
  k_thx<<<32768, 256, 0, stream>>>(buf0, buf2, out1T, out2T, out1H, out2H,
                                   invn1h, invn1w, invn2w);          // T/H + norm partials
  k_finw<<<96, 256, 0, stream>>>(invn1h);                            // finalize all 3 norms
  k_attnS_m<<<128, 256, 0, stream>>>(out1T, out2T, out1H,
                                     invn1h, invn1w, invn2w, A1b, A2b);
  k_o34f<<<1024, 256, 0, stream>>>(A1b, out1T, out1H, invn1w,
                                   out2H, A2b, buf2, invn2w, o34b);  // o34 bf16 = o3+o4+q2+q1
  k_nhwcb<<<16384, 256, 0, stream>>>(o34b, ob);                      // ob (out1H dead)
  k_mconv1<<<1024, 256, 0, stream>>>(ob, wbo2, x, out, 0, nullptr);  // final + x (T dead)
}

// Round 12
// 739.424 us; speedup vs baseline: 1.0350x; 1.0055x over previous
//
#include <hip/hip_runtime.h>

#define Bb 8
#define Cc 128
#define Hh 128
#define Ww 128
#define HW 16384
#define CHW (Cc*HW)
#define NHW (Bb*HW)
#define CH 16
#define EPS 1e-5f
#define NSLICE 16

typedef __attribute__((ext_vector_type(8))) short bf16x8;
typedef __attribute__((ext_vector_type(4))) float f32x4;

static __device__ __forceinline__ short f2b(float f) {
  unsigned u = __float_as_uint(f);
  unsigned lsb = (u >> 16) & 1;
  return (short)((u + 0x7fffu + lsb) >> 16);
}
static __device__ __forceinline__ float b2f(short s) {
  return __uint_as_float(((unsigned)(unsigned short)s) << 16);
}
static __device__ __forceinline__ int pack2(short lo, short hi) {
  return ((int)(unsigned short)hi << 16) | (unsigned short)lo;
}

// per-wave 16-lane butterfly + atomic stats update, SHARDED 16 ways by blockIdx
static __device__ __forceinline__ void stats_epilogue(
    float* __restrict__ statp, f32x4 acc[4][4], int co0, int quad, int lm)
{
  statp += (blockIdx.x & (NSLICE-1)) * 768;
  #pragma unroll
  for (int i = 0; i < 4; ++i) {
    f32x4 s = acc[i][0] + acc[i][1] + acc[i][2] + acc[i][3];
    f32x4 q = acc[i][0]*acc[i][0] + acc[i][1]*acc[i][1]
            + acc[i][2]*acc[i][2] + acc[i][3]*acc[i][3];
    #pragma unroll
    for (int m = 1; m < 16; m <<= 1) {
      #pragma unroll
      for (int e = 0; e < 4; ++e) {
        s[e] += __shfl_xor(s[e], m);
        q[e] += __shfl_xor(q[e], m);
      }
    }
    if (lm == 0) {
      int co = co0 + i*16 + quad*4;
      #pragma unroll
      for (int e = 0; e < 4; ++e) {
        atomicAdd(&statp[co + e], s[e]);
        atomicAdd(&statp[128 + co + e], q[e]);
      }
    }
  }
}

// ---------------- LayerNorm over channel dim ----------------
__global__ __launch_bounds__(256) void k_ln(const float* __restrict__ x,
    const float* __restrict__ g, const float* __restrict__ be,
    float* __restrict__ y)
{
  int p = blockIdx.x*256 + threadIdx.x;
  int b = p >> 14, hw = p & 16383;
  const float* xp = x + (long)b*CHW + hw;
  float s = 0.f, q = 0.f;
  for (int c = 0; c < Cc; ++c) { float v = xp[c*HW]; s += v; q += v*v; }
  float mu = s * (1.f/Cc);
  float var = q * (1.f/Cc) - mu*mu;
  float rstd = rsqrtf(var + EPS);
  float* yp = y + (long)b*CHW + hw;
  for (int c = 0; c < Cc; ++c) {
    float v = xp[c*HW];
    yp[c*HW] = (v - mu) * rstd * g[c] + be[c];
  }
}

// ---------------- 3x3 weight: [co][ci][tap] fp32 -> [tap][co][ci] bf16 ----------------
__global__ __launch_bounds__(256) void k_reorg3b(const float* __restrict__ Wt, short* __restrict__ out)
{
  int idx = blockIdx.x*256 + threadIdx.x;
  int tap = idx >> 14, r = idx & 16383;
  out[idx] = f2b(Wt[r*9 + tap]);
}

__global__ __launch_bounds__(256) void k_cast(const float* __restrict__ in, short* __restrict__ out)
{
  int i = blockIdx.x*256 + threadIdx.x;
  out[i] = f2b(in[i]);
}

__global__ __launch_bounds__(256) void k_zero(float* p, int n)
{
  int i = blockIdx.x*256 + threadIdx.x;
  if (i < n) p[i] = 0.f;
}

// ---------------- NCHW fp32 -> NHWC bf16 (packed int2 stores) ----------------
__global__ __launch_bounds__(256) void k_nhwc(const float* __restrict__ in, short* __restrict__ out)
{
  __shared__ float Ls[32][33];
  int bid = blockIdx.x;
  int hwt = bid & 511, c4 = (bid>>9)&3, b = bid>>11;
  int hw0 = hwt << 5, c0 = c4 << 5;
  int t = threadIdx.x;
  int hl = t & 31, cl = t >> 5;
  const float* p = in + (long)b*CHW + hw0;
  for (int r = cl; r < 32; r += 8)
    Ls[r][hl] = p[(long)(c0+r)*HW + hl];
  __syncthreads();
  short* q = out + ((long)b*HW + hw0)*Cc + c0;
  int hwrow = t >> 3, cgrp = t & 7;     // 32 rows x 8 groups of 4 c
  short v[4];
  #pragma unroll
  for (int e = 0; e < 4; ++e) v[e] = f2b(Ls[cgrp*4 + e][hwrow]);
  int2 o;
  o.x = pack2(v[0], v[1]);
  o.y = pack2(v[2], v[3]);
  *(int2*)(q + (long)hwrow*Cc + cgrp*4) = o;
}

// ---------------- NCHW bf16 -> NHWC bf16 (no re-round, packed int2 stores) ----
__global__ __launch_bounds__(256) void k_nhwcb(const short* __restrict__ in, short* __restrict__ out)
{
  __shared__ short Ls[32][34];
  int bid = blockIdx.x;
  int hwt = bid & 511, c4 = (bid>>9)&3, b = bid>>11;
  int hw0 = hwt << 5, c0 = c4 << 5;
  int t = threadIdx.x;
  int hl = t & 31, cl = t >> 5;
  const short* p = in + (long)b*CHW + hw0;
  for (int r = cl; r < 32; r += 8)
    Ls[r][hl] = p[(long)(c0+r)*HW + hl];
  __syncthreads();
  short* q = out + ((long)b*HW + hw0)*Cc + c0;
  int hwrow = t >> 3, cgrp = t & 7;
  short v[4];
  #pragma unroll
  for (int e = 0; e < 4; ++e) v[e] = Ls[cgrp*4 + e][hwrow];
  int2 o;
  o.x = pack2(v[0], v[1]);
  o.y = pack2(v[2], v[3]);
  *(int2*)(q + (long)hwrow*Cc + cgrp*4) = o;
}

// ---------------- MFMA conv, dilated 3x3, full-K LDS tiles, NHWC fp32 output ----
__global__ __launch_bounds__(256,2) void k_mconv(const short* __restrict__ X,
    const short* __restrict__ W, float* __restrict__ Y, int k3, int dil,
    float* __restrict__ statp)
{
  __shared__ short Ws[128*136];
  __shared__ short Xs[152*136];
  int b = blockIdx.x >> 7, h = blockIdx.x & 127;
  int t = threadIdx.x;
  int wave = t >> 6, lane = t & 63;
  int co0 = (wave >> 1) << 6, sp0 = (wave & 1) << 6;
  int lm = lane & 15, quad = lane >> 4;
  f32x4 acc[4][4];
  #pragma unroll
  for (int i = 0; i < 4; ++i)
    #pragma unroll
    for (int j = 0; j < 4; ++j) acc[i][j] = (f32x4){0.f,0.f,0.f,0.f};
  int half = k3 >> 1;

  {
    f32x4 z = {0.f,0.f,0.f,0.f};
    for (int i = t; i < 408; i += 256) {        // 24 halo rows x 17 f32x4
      int r = i / 17, o = i - r*17;
      int row = r < 12 ? r : r + 128;
      *(f32x4*)(Xs + row*136 + o*8) = z;
    }
  }

  for (int kh = 0; kh < k3; ++kh) {
    int hs = h + (kh - half)*dil;
    if ((unsigned)hs >= (unsigned)Hh) continue;
    __syncthreads();
    {
      const short* xr = X + ((long)(b*Hh + hs)*Ww)*Cc;
      #pragma unroll
      for (int it = 0; it < 8; ++it) {
        int i = t + it*256;
        int row = i >> 4, off = (i & 15) << 3;
        *(f32x4*)(Xs + (12 + row)*136 + off) = *(const f32x4*)(xr + (long)row*Cc + off);
      }
    }
    for (int kw = 0; kw < k3; ++kw) {
      int dw = (kw - half)*dil;
      if (kw) __syncthreads();
      {
        const short* wt = W + (kh*k3 + kw)*16384;
        #pragma unroll
        for (int it = 0; it < 8; ++it) {
          int i = t + it*256;
          int row = i >> 4, off = (i & 15) << 3;
          *(f32x4*)(Ws + row*136 + off) = *(const f32x4*)(wt + (long)row*128 + off);
        }
      }
      __syncthreads();
      int xrow0 = 12 + dw + sp0;
      for (int kc = 0; kc < 4; ++kc) {
        int k0 = kc << 5;
        bf16x8 af[4], bfr[4];
        #pragma unroll
        for (int i = 0; i < 4; ++i)
          af[i] = *(const bf16x8*)(Ws + (co0 + i*16 + lm)*136 + k0 + quad*8);
        #pragma unroll
        for (int j = 0; j < 4; ++j)
          bfr[j] = *(const bf16x8*)(Xs + (xrow0 + j*16 + lm)*136 + k0 + quad*8);
        #pragma unroll
        for (int i = 0; i < 4; ++i)
          #pragma unroll
          for (int j = 0; j < 4; ++j)
            acc[i][j] = __builtin_amdgcn_mfma_f32_16x16x32_bf16(af[i], bfr[j], acc[i][j], 0, 0, 0);
      }
    }
  }
  float* yb = Y + ((long)(b*Hh + h)*Ww)*Cc;
  #pragma unroll
  for (int i = 0; i < 4; ++i) {
    int co = co0 + i*16 + quad*4;
    #pragma unroll
    for (int j = 0; j < 4; ++j) {
      int wc = sp0 + j*16 + lm;
      *(f32x4*)(yb + (long)wc*Cc + co) = acc[i][j];
    }
  }
  if (statp) stats_epilogue(statp, acc, co0, quad, lm);
}

// ---------------- MFMA 1x1 conv: weights in LDS, X fragments direct from global ----
__global__ __launch_bounds__(256,4) void k_mconv1(const short* __restrict__ X,
    const short* __restrict__ W, const float* __restrict__ res,
    float* __restrict__ Y, int nhwc, float* __restrict__ statp)
{
  __shared__ short Ws[128*136];
  int b = blockIdx.x >> 7, h = blockIdx.x & 127;
  int t = threadIdx.x;
  int wave = t >> 6, lane = t & 63;
  int co0 = (wave >> 1) << 6, sp0 = (wave & 1) << 6;
  int lm = lane & 15, quad = lane >> 4;
  #pragma unroll
  for (int it = 0; it < 8; ++it) {
    int i = t + it*256;
    int row = i >> 4, off = (i & 15) << 3;
    *(f32x4*)(Ws + row*136 + off) = *(const f32x4*)(W + (long)row*128 + off);
  }
  f32x4 acc[4][4];
  #pragma unroll
  for (int i = 0; i < 4; ++i)
    #pragma unroll
    for (int j = 0; j < 4; ++j) acc[i][j] = (f32x4){0.f,0.f,0.f,0.f};
  const short* xr = X + ((long)(b*Hh + h)*Ww)*Cc;
  __syncthreads();
  #pragma unroll
  for (int kc = 0; kc < 4; ++kc) {
    int k0 = kc << 5;
    bf16x8 af[4], bfr[4];
    #pragma unroll
    for (int j = 0; j < 4; ++j)
      bfr[j] = *(const bf16x8*)(xr + (long)(sp0 + j*16 + lm)*Cc + k0 + quad*8);
    #pragma unroll
    for (int i = 0; i < 4; ++i)
      af[i] = *(const bf16x8*)(Ws + (co0 + i*16 + lm)*136 + k0 + quad*8);
    #pragma unroll
    for (int i = 0; i < 4; ++i)
      #pragma unroll
      for (int j = 0; j < 4; ++j)
        acc[i][j] = __builtin_amdgcn_mfma_f32_16x16x32_bf16(af[i], bfr[j], acc[i][j], 0, 0, 0);
  }
  if (nhwc) {
    float* yb = Y + ((long)(b*Hh + h)*Ww)*Cc;
    #pragma unroll
    for (int i = 0; i < 4; ++i) {
      int co = co0 + i*16 + quad*4;
      #pragma unroll
      for (int j = 0; j < 4; ++j) {
        int wc = sp0 + j*16 + lm;
        *(f32x4*)(yb + (long)wc*Cc + co) = acc[i][j];
      }
    }
    if (statp) stats_epilogue(statp, acc, co0, quad, lm);
  } else {
    __syncthreads();                       // all waves done reading Ws
    float* scr = (float*)Ws + wave*320;    // 16 rows x stride 20 f32, wave-private
    int co_l = lane >> 2, wq = (lane & 3) << 2;
    #pragma unroll
    for (int i = 0; i < 4; ++i) {
      #pragma unroll
      for (int j = 0; j < 4; ++j) {
        #pragma unroll
        for (int r = 0; r < 4; ++r)
          scr[(quad*4 + r)*20 + lm] = acc[i][j][r];
        f32x4 vv = *(f32x4*)(scr + co_l*20 + wq);
        int co = co0 + i*16 + co_l;
        int wc = sp0 + j*16 + wq;
        long idx = ((long)(b*Cc + co)*Hh + h)*Ww + wc;
        if (res) vv += *(const f32x4*)(res + idx);
        *(f32x4*)(Y + idx) = vv;
      }
    }
  }
}

// ---------------- BN finalize: sum 16 slices -> per-channel scale/offset ----------------
__global__ __launch_bounds__(128) void k_bnfin(const float* __restrict__ stats,
    const float* __restrict__ g1, const float* __restrict__ be1,
    const float* __restrict__ g2, const float* __restrict__ be2,
    const float* __restrict__ g3, const float* __restrict__ be3,
    float* __restrict__ so)
{
  int c = threadIdx.x;
  const float inv = 1.f/(float)NHW;
  const float* gs[3] = {g1, g2, g3};
  const float* bs[3] = {be1, be2, be3};
  #pragma unroll
  for (int tsel = 0; tsel < 3; ++tsel) {
    float su = 0.f, qu = 0.f;
    for (int sl = 0; sl < NSLICE; ++sl) {
      su += stats[sl*768 + tsel*256 + c];
      qu += stats[sl*768 + tsel*256 + 128 + c];
    }
    float mu = su*inv;
    float var = qu*inv - mu*mu;
    float s = rsqrtf(var + EPS)*gs[tsel][c];
    so[tsel*256 + c] = s;
    so[tsel*256 + 128 + c] = bs[tsel][c] - mu*s;
  }
}

// ---------------- BN apply + relu, sum three branches (NHWC in) -> sb bf16 NHWC ----
__global__ __launch_bounds__(256) void k_bnapply(const float* __restrict__ y1,
    const float* __restrict__ y2, const float* __restrict__ y3,
    const float* __restrict__ so, short* __restrict__ sb)
{
  long e = ((long)blockIdx.x*256 + threadIdx.x) * 8;
  int c = (int)(e & 127);
  f32x4 s1a = *(const f32x4*)(so + c),        s1b = *(const f32x4*)(so + c + 4);
  f32x4 o1a = *(const f32x4*)(so + 128 + c),  o1b = *(const f32x4*)(so + 132 + c);
  f32x4 s2a = *(const f32x4*)(so + 256 + c),  s2b = *(const f32x4*)(so + 260 + c);
  f32x4 o2a = *(const f32x4*)(so + 384 + c),  o2b = *(const f32x4*)(so + 388 + c);
  f32x4 s3a = *(const f32x4*)(so + 512 + c),  s3b = *(const f32x4*)(so + 516 + c);
  f32x4 o3a = *(const f32x4*)(so + 640 + c),  o3b = *(const f32x4*)(so + 644 + c);
  f32x4 v1a = *(const f32x4*)(y1 + e), v1b = *(const f32x4*)(y1 + e + 4);
  f32x4 v2a = *(const f32x4*)(y2 + e), v2b = *(const f32x4*)(y2 + e + 4);
  f32x4 v3a = *(const f32x4*)(y3 + e), v3b = *(const f32x4*)(y3 + e + 4);
  float r[8];
  #pragma unroll
  for (int k = 0; k < 4; ++k) {
    r[k] = fmaxf(fmaf(v1a[k], s1a[k], o1a[k]), 0.f)
         + fmaxf(fmaf(v2a[k], s2a[k], o2a[k]), 0.f)
         + fmaxf(fmaf(v3a[k], s3a[k], o3a[k]), 0.f);
    r[4+k] = fmaxf(fmaf(v1b[k], s1b[k], o1b[k]), 0.f)
           + fmaxf(fmaf(v2b[k], s2b[k], o2b[k]), 0.f)
           + fmaxf(fmaf(v3b[k], s3b[k], o3b[k]), 0.f);
  }
  int4 o;
  o.x = pack2(f2b(r[0]), f2b(r[1]));
  o.y = pack2(f2b(r[2]), f2b(r[3]));
  o.z = pack2(f2b(r[4]), f2b(r[5]));
  o.w = pack2(f2b(r[6]), f2b(r[7]));
  *(int4*)(sb + e) = o;
}

// ---------------- six depthwise branches summed, LDS-tiled stencil, bf16 out ----
__global__ __launch_bounds__(256) void k_dw2(const float* __restrict__ X,
    const float* __restrict__ w1, const float* __restrict__ b1,
    const float* __restrict__ w2, const float* __restrict__ b2,
    const float* __restrict__ w3, const float* __restrict__ b3,
    const float* __restrict__ w4, const float* __restrict__ b4,
    const float* __restrict__ w5, const float* __restrict__ b5,
    const float* __restrict__ w6, const float* __restrict__ b6,
    short* __restrict__ Y)
{
  __shared__ float Ls[38][136];
  int bid = blockIdx.x;
  int tile = bid & 3, plane = bid >> 2;
  int c = plane & 127;
  int h0 = tile << 5;
  int t = threadIdx.x;

  float hcoef[7], vcoef[7], k9[9];
  #pragma unroll
  for (int d = 0; d < 7; ++d) { hcoef[d] = w5[c*7+d]; vcoef[d] = w6[c*7+d]; }
  #pragma unroll
  for (int d = 1; d < 6; ++d) { hcoef[d] += w1[c*5+d-1]; vcoef[d] += w2[c*5+d-1]; }
  hcoef[3] += w3[c];
  #pragma unroll
  for (int k = 0; k < 9; ++k) k9[k] = w4[c*9+k];
  float bias = b1[c]+b2[c]+b3[c]+b4[c]+b5[c]+b6[c];

  const float* xp = X + (long)plane*HW;

  f32x4* lz = (f32x4*)&Ls[0][0];
  for (int i = t; i < 1292; i += 256) lz[i] = (f32x4){0.f,0.f,0.f,0.f};
  __syncthreads();
  for (int i = t; i < 1216; i += 256) {
    int r = i >> 5, cg = (i & 31) << 2;
    int h = h0 - 3 + r;
    if ((unsigned)h < 128u)
      *(f32x4*)&Ls[r][4 + cg] = *(const f32x4*)(xp + h*128 + cg);
  }
  __syncthreads();

  int g = t & 31, rs = t >> 5;
  int w0 = g << 2;
  short* Yp = Y + (long)plane*HW;

  for (int ro = 0; ro < 4; ++ro) {
    int lr = rs + (ro << 3);
    int R = lr + 3;
    f32x4 a0 = *(const f32x4*)&Ls[R][w0];
    f32x4 a1 = *(const f32x4*)&Ls[R][w0+4];
    f32x4 a2 = *(const f32x4*)&Ls[R][w0+8];
    f32x4 u0 = *(const f32x4*)&Ls[R-1][w0];
    f32x4 u1 = *(const f32x4*)&Ls[R-1][w0+4];
    f32x4 u2 = *(const f32x4*)&Ls[R-1][w0+8];
    f32x4 d0 = *(const f32x4*)&Ls[R+1][w0];
    f32x4 d1 = *(const f32x4*)&Ls[R+1][w0+4];
    f32x4 d2 = *(const f32x4*)&Ls[R+1][w0+8];
    f32x4 v3u = *(const f32x4*)&Ls[R-3][w0+4];
    f32x4 v2u = *(const f32x4*)&Ls[R-2][w0+4];
    f32x4 v2d = *(const f32x4*)&Ls[R+2][w0+4];
    f32x4 v3d = *(const f32x4*)&Ls[R+3][w0+4];

    float cr[12], ur[12], dr[12];
    #pragma unroll
    for (int k = 0; k < 4; ++k) {
      cr[k] = a0[k]; cr[4+k] = a1[k]; cr[8+k] = a2[k];
      ur[k] = u0[k]; ur[4+k] = u1[k]; ur[8+k] = u2[k];
      dr[k] = d0[k]; dr[4+k] = d1[k]; dr[8+k] = d2[k];
    }

    float o[4];
    #pragma unroll
    for (int j = 0; j < 4; ++j) {
      float acc = bias;
      #pragma unroll
      for (int d = 0; d < 7; ++d) acc = fmaf(hcoef[d], cr[j+d+1], acc);
      acc = fmaf(vcoef[0], v3u[j], acc);
      acc = fmaf(vcoef[1], v2u[j], acc);
      acc = fmaf(vcoef[2], ur[j+4], acc);
      acc = fmaf(vcoef[3], cr[j+4], acc);
      acc = fmaf(vcoef[4], dr[j+4], acc);
      acc = fmaf(vcoef[5], v2d[j], acc);
      acc = fmaf(vcoef[6], v3d[j], acc);
      #pragma unroll
      for (int kw = 0; kw < 3; ++kw) {
        acc = fmaf(k9[kw],   ur[j+3+kw], acc);
        acc = fmaf(k9[3+kw], cr[j+3+kw], acc);
        acc = fmaf(k9[6+kw], dr[j+3+kw], acc);
      }
      o[j] = acc;
    }
    int2 ov;
    ov.x = pack2(f2b(o[0]), f2b(o[1]));
    ov.y = pack2(f2b(o[2]), f2b(o[3]));
    *(int2*)(Yp + (h0 + lr)*128 + w0) = ov;
  }
}

// ---------------- finalize: acc -> 1/max(sqrt(acc),1e-12), in place ----------------
__global__ __launch_bounds__(256) void k_finw(float* __restrict__ p)
{
  int i = blockIdx.x*256 + threadIdx.x;
  float v = p[i];
  p[i] = 1.f/fmaxf(sqrtf(v), 1e-12f);
}

// ---------------- fused transpose+cast+NORM, packed int4 stores ----------------
// Per 32x32 tile: out?T (transposed bf16) + out?H + row/col norm partials.
// Threads 0-127 store T (each 8 consecutive h of one w-row, int4 = 16B);
// threads 128-255 store H (each 8 consecutive w of one h-row, int4).
__global__ __launch_bounds__(256) void k_thx(const float* __restrict__ out1,
    const float* __restrict__ out2,
    short* __restrict__ out1T, short* __restrict__ out2T,
    short* __restrict__ out1H, short* __restrict__ out2H,
    float* __restrict__ n1h, float* __restrict__ n1w, float* __restrict__ n2w)
{
  __shared__ float Ls[32][33];
  int bid = blockIdx.x;
  int wt = bid&3, ht=(bid>>2)&3, c=(bid>>4)&127, b=(bid>>11)&7, src=bid>>14;
  const float* in = (src ? out2 : out1) + (long)(b*128+c)*16384;
  long tbase = ((long)(b*8 + (c>>4))*128)*2048 + (c&15)*128;
  short* pT = (src ? out2T : out1T) + tbase;
  short* pH; long hstr;
  if (src) { pH = out2H + (long)(b*128+c)*16384; hstr = 128; }
  else     { pH = out1H + tbase;                 hstr = 2048; }
  int h0 = ht*32, w0 = wt*32;
  int t = threadIdx.x, li = t&31, r0 = t>>5;
  for (int r = r0; r < 32; r += 8)
    Ls[r][li] = in[(h0+r)*128 + w0 + li];
  __syncthreads();
  int bhbase = (b*8 + (c>>4))*128;
  if (t < 32) {
    if (!src) {
      float s = 0.f;
      for (int k = 0; k < 32; ++k) { float v = Ls[t][k]; s += v*v; }
      atomicAdd(&n1h[bhbase + h0 + t], s);
    }
  } else if (t < 64) {
    int w = t - 32;
    float s = 0.f;
    for (int k = 0; k < 32; ++k) { float v = Ls[k][w]; s += v*v; }
    atomicAdd((src ? n2w : n1w) + bhbase + w0 + w, s);
  }
  if (t < 128) {
    int wrow = t >> 2, hgrp = t & 3;     // T: value(w0+wrow, h0+hgrp*8+e) = Ls[h][w]
    short v[8];
    #pragma unroll
    for (int e = 0; e < 8; ++e) v[e] = f2b(Ls[hgrp*8 + e][wrow]);
    int4 o;
    o.x = pack2(v[0], v[1]);
    o.y = pack2(v[2], v[3]);
    o.z = pack2(v[4], v[5]);
    o.w = pack2(v[6], v[7]);
    *(int4*)(pT + (long)(w0 + wrow)*2048 + h0 + hgrp*8) = o;
  } else {
    int k2 = t - 128;
    int hrow = k2 >> 2, wgrp = k2 & 3;   // H: value(h0+hrow, w0+wgrp*8+e) = Ls[h][w]
    short v[8];
    #pragma unroll
    for (int e = 0; e < 8; ++e) v[e] = f2b(Ls[hrow][wgrp*8 + e]);
    int4 o;
    o.x = pack2(v[0], v[1]);
    o.y = pack2(v[2], v[3]);
    o.z = pack2(v[4], v[5]);
    o.w = pack2(v[6], v[7]);
    *(int4*)(pH + (long)(h0 + hrow)*hstr + w0 + wgrp*8) = o;
  }
}

// ---------------- MFMA attention S + softmax -> A1/A2 (bf16 row-major) ----------------
// grid 128 = type(2) x bh(64). Block: 128 rows x 128 cols, K=2048.
__global__ __launch_bounds__(256) void k_attnS_m(
    const short* __restrict__ out1T, const short* __restrict__ out2T,
    const short* __restrict__ out1H,
    const float* __restrict__ invn1h, const float* __restrict__ invn1w,
    const float* __restrict__ invn2w,
    short* __restrict__ A1b, short* __restrict__ A2b)
{
  __shared__ short As[128*72];
  __shared__ short Bs[128*72];
  int bid = blockIdx.x;
  int type = bid >> 6, bh = bid & 63;
  const short* Aop = (type ? out1T : out2T) + (long)bh*262144;
  const short* Bop = (type ? out2T : out1H) + (long)bh*262144;
  const float* invrow = (type ? invn1w : invn2w) + bh*128;
  const float* invcol = (type ? invn2w : invn1h) + bh*128;
  short* Aout = (type ? A2b : A1b) + (long)bh*16384;
  int t = threadIdx.x;
  int wave = t >> 6, lane = t & 63, lm = lane & 15, quad = lane >> 4;
  int m0 = wave << 5;
  f32x4 acc[2][8];
  #pragma unroll
  for (int i = 0; i < 2; ++i)
    #pragma unroll
    for (int j = 0; j < 8; ++j) acc[i][j] = (f32x4){0.f,0.f,0.f,0.f};
  for (int kc = 0; kc < 32; ++kc) {
    int k0 = kc << 6;
    __syncthreads();
    #pragma unroll
    for (int i = 0; i < 4; ++i) {
      int e = t + i*256;
      int row = e >> 3, off = (e & 7) << 3;
      *(float4*)(As + row*72 + off) = *(const float4*)(Aop + (long)row*2048 + k0 + off);
      *(float4*)(Bs + row*72 + off) = *(const float4*)(Bop + (long)row*2048 + k0 + off);
    }
    __syncthreads();
    #pragma unroll
    for (int ks = 0; ks < 64; ks += 32) {
      bf16x8 af[2], bfj[8];
      #pragma unroll
      for (int i = 0; i < 2; ++i)
        af[i] = *(const bf16x8*)(As + (m0 + i*16 + lm)*72 + ks + quad*8);
      #pragma unroll
      for (int j = 0; j < 8; ++j)
        bfj[j] = *(const bf16x8*)(Bs + (j*16 + lm)*72 + ks + quad*8);
      #pragma unroll
      for (int i = 0; i < 2; ++i)
        #pragma unroll
        for (int j = 0; j < 8; ++j)
          acc[i][j] = __builtin_amdgcn_mfma_f32_16x16x32_bf16(af[i], bfj[j], acc[i][j], 0, 0, 0);
    }
  }
  float colv[8];
  #pragma unroll
  for (int j = 0; j < 8; ++j) colv[j] = invcol[j*16 + lm];
  #pragma unroll
  for (int i = 0; i < 2; ++i) {
    #pragma unroll
    for (int r = 0; r < 4; ++r) {
      int row = m0 + i*16 + quad*4 + r;
      float rs = invrow[row];
      float sv[8];
      float mx = -1e30f;
      #pragma unroll
      for (int j = 0; j < 8; ++j) {
        sv[j] = acc[i][j][r] * rs * colv[j];
        mx = fmaxf(mx, sv[j]);
      }
      mx = fmaxf(mx, __shfl_xor(mx, 1));
      mx = fmaxf(mx, __shfl_xor(mx, 2));
      mx = fmaxf(mx, __shfl_xor(mx, 4));
      mx = fmaxf(mx, __shfl_xor(mx, 8));
      float sum = 0.f;
      #pragma unroll
      for (int j = 0; j < 8; ++j) { sv[j] = __expf(sv[j] - mx); sum += sv[j]; }
      sum += __shfl_xor(sum, 1);
      sum += __shfl_xor(sum, 2);
      sum += __shfl_xor(sum, 4);
      sum += __shfl_xor(sum, 8);
      float inv = 1.f/sum;
      #pragma unroll
      for (int j = 0; j < 8; ++j)
        Aout[row*128 + j*16 + lm] = f2b(sv[j]*inv);
    }
  }
}

// ---------------- fused o34: o3 + o4 + q2 + q1, single bf16 write ----------------
__global__ __launch_bounds__(256) void k_o34f(
    const short* __restrict__ A1b, const short* __restrict__ out1T,
    const short* __restrict__ out1H, const float* __restrict__ invn1w,
    const short* __restrict__ out2H, const short* __restrict__ A2b,
    const float* __restrict__ out2, const float* __restrict__ invn2w,
    short* __restrict__ o34b)
{
  __shared__ short As[128*72];
  __shared__ short Bs[128*72];
  int bid = blockIdx.x;
  int cf = bid & 127, b = bid >> 7;
  int hd = cf >> 4, c = cf & 15;
  int bh = b*8 + hd;
  const short* A0 = A1b + (long)bh*16384;              // [h][k] stride 128
  const short* B0 = out1T + (long)bh*262144 + c*128;   // [w][k] stride 2048
  const short* A1_ = out2H + (long)(b*128 + cf)*16384; // [h][k] stride 128
  const short* B1_ = A2b + (long)bh*16384;             // [w][k] stride 128
  const short* R = out1H + (long)bh*262144 + c*128;    // q2 operand, stride 2048
  const float* o2p = out2 + (long)(b*128 + cf)*16384;  // q1 operand (transposed read)
  const float* inw1 = invn1w + bh*128;
  const float* inw2 = invn2w + bh*128;
  short* O = o34b + (long)(b*128 + cf)*16384;
  int t = threadIdx.x;
  int wave = t >> 6, lane = t & 63, lm = lane & 15, quad = lane >> 4;
  int m0 = (wave >> 1) << 6, n0 = (wave & 1) << 6;
  f32x4 acc[4][4];
  #pragma unroll
  for (int i = 0; i < 4; ++i)
    #pragma unroll
    for (int j = 0; j < 4; ++j) acc[i][j] = (f32x4){0.f,0.f,0.f,0.f};
  for (int g = 0; g < 4; ++g) {
    const short* Asrc = (g < 2) ? A0 : A1_;
    const short* Bsrc = (g < 2) ? B0 : B1_;
    long Bst = (g < 2) ? 2048 : 128;
    int k0 = (g & 1) << 6;
    __syncthreads();
    #pragma unroll
    for (int i = 0; i < 4; ++i) {
      int e = t + i*256;
      int row = e >> 3, off = (e & 7) << 3;
      *(float4*)(As + row*72 + off) = *(const float4*)(Asrc + (long)row*128 + k0 + off);
      *(float4*)(Bs + row*72 + off) = *(const float4*)(Bsrc + (long)row*Bst + k0 + off);
    }
    __syncthreads();
    #pragma unroll
    for (int ks = 0; ks < 64; ks += 32) {
      bf16x8 af[4], bfj[4];
      #pragma unroll
      for (int i = 0; i < 4; ++i)
        af[i] = *(const bf16x8*)(As + (m0 + i*16 + lm)*72 + ks + quad*8);
      #pragma unroll
      for (int j = 0; j < 4; ++j)
        bfj[j] = *(const bf16x8*)(Bs + (n0 + j*16 + lm)*72 + ks + quad*8);
      #pragma unroll
      for (int i = 0; i < 4; ++i)
        #pragma unroll
        for (int j = 0; j < 4; ++j)
          acc[i][j] = __builtin_amdgcn_mfma_f32_16x16x32_bf16(af[i], bfj[j], acc[i][j], 0, 0, 0);
    }
  }
  // q2 + q1 in register layout (row = m0+i*16+quad*4+r, col = n0+j*16+lm)
  float inwv[4];
  #pragma unroll
  for (int j = 0; j < 4; ++j) inwv[j] = inw1[n0 + j*16 + lm];
  #pragma unroll
  for (int i = 0; i < 4; ++i) {
    int row0 = m0 + i*16 + quad*4;
    f32x4 iv2 = *(const f32x4*)(inw2 + row0);
    #pragma unroll
    for (int j = 0; j < 4; ++j) {
      int col = n0 + j*16 + lm;
      f32x4 vq = *(const f32x4*)(o2p + (long)col*128 + row0);
      #pragma unroll
      for (int r = 0; r < 4; ++r)
        acc[i][j][r] += b2f(R[(long)(row0 + r)*2048 + col]) * inwv[j]
                      + vq[r] * iv2[r];
    }
  }
  // LDS-transposed store: 4 bf16 (8B) contiguous in w per thread
  __syncthreads();
  float* scr = (float*)As + wave*320;
  int co_l = lane >> 2, wq = (lane & 3) << 2;
  #pragma unroll
  for (int i = 0; i < 4; ++i) {
    #pragma unroll
    for (int j = 0; j < 4; ++j) {
      #pragma unroll
      for (int r = 0; r < 4; ++r)
        scr[(quad*4 + r)*20 + lm] = acc[i][j][r];
      f32x4 vv = *(f32x4*)(scr + co_l*20 + wq);
      int2 ov;
      ov.x = pack2(f2b(vv[0]), f2b(vv[1]));
      ov.y = pack2(f2b(vv[2]), f2b(vv[3]));
      *(int2*)(O + (long)(m0 + i*16 + co_l)*128 + n0 + j*16 + wq) = ov;
    }
  }
}

extern "C" void kernel_launch(void* const* d_in, const int* in_sizes, int n_in,
                              void* d_out, int out_size, void* d_ws, size_t ws_size,
                              hipStream_t stream)
{
  const float* x    = (const float*)d_in[0];
  const float* ln_w = (const float*)d_in[1];
  const float* ln_b = (const float*)d_in[2];
  const float* wd1  = (const float*)d_in[3];
  const float* gd1  = (const float*)d_in[4];
  const float* bd1  = (const float*)d_in[5];
  const float* wd2  = (const float*)d_in[6];
  const float* gd2  = (const float*)d_in[7];
  const float* bd2  = (const float*)d_in[8];
  const float* wd3  = (const float*)d_in[9];
  const float* gd3  = (const float*)d_in[10];
  const float* bd3  = (const float*)d_in[11];
  const float* w_out1 = (const float*)d_in[12];
  const float* w1 = (const float*)d_in[13]; const float* b1 = (const float*)d_in[14];
  const float* w2 = (const float*)d_in[15]; const float* b2 = (const float*)d_in[16];
  const float* w3 = (const float*)d_in[17]; const float* b3 = (const float*)d_in[18];
  const float* w4 = (const float*)d_in[19]; const float* b4 = (const float*)d_in[20];
  const float* w5 = (const float*)d_in[21]; const float* b5 = (const float*)d_in[22];
  const float* w6 = (const float*)d_in[23]; const float* b6 = (const float*)d_in[24];
  const float* w_out2 = (const float*)d_in[25];
  float* out = (float*)d_out;

  const long SLAB = 16777216L;
  float* buf0 = (float*)d_ws;            // xb -> sb -> x1 -> out1 -> o34b
  float* buf1 = buf0 + SLAB;             // y1 -> ab -> out1H|out2H -> ob
  float* buf2 = buf1 + SLAB;             // y2 -> out2
  float* dbuf = out;                     // y3 -> att(bf16) -> out1T|out2T -> final
  float* stats = buf2 + SLAB;            // 16 slices x 768
  float* invn1h = stats + NSLICE*768;    // 3 x 8192 accumulators (contiguous)
  float* invn1w = invn1h + 8192;
  float* invn2w = invn1w + 8192;
  short* wb2  = (short*)(invn2w + 8192);
  short* wb3  = wb2 + 147456;
  short* wb1  = wb3 + 147456;
  short* wbo1 = wb1 + 16384;
  short* wbo2 = wbo1 + 16384;
  short* A1b  = wbo2 + 16384;
  short* A2b  = A1b + 1048576;
  float* bnso = (float*)(A2b + 1048576); // 768 floats: BN scale/offset

  short* xb = (short*)buf0;
  short* sb = (short*)buf0;              // overwrites xb (dead after y-convs)
  short* attb = (short*)dbuf;            // bf16 att (overwrites y3, dead)
  short* ab = (short*)buf1;
  short* out1T = (short*)dbuf;
  short* out2T = out1T + 16777216;
  short* out1H = (short*)buf1;
  short* out2H = out1H + 16777216;
  short* o34b = (short*)buf0;            // bf16 o34 (out1 fp32 dead by then)
  short* ob = (short*)buf1;              // overwrites out1H (dead by then)

  k_zero<<<48, 256, 0, stream>>>(stats, NSLICE*768);
  k_zero<<<96, 256, 0, stream>>>(invn1h, 24576);   // all 3 norm accumulators
  k_reorg3b<<<576, 256, 0, stream>>>(wd2, wb2);
  k_reorg3b<<<576, 256, 0, stream>>>(wd3, wb3);
  k_cast<<<64, 256, 0, stream>>>(wd1, wb1);
  k_cast<<<64, 256, 0, stream>>>(w_out1, wbo1);
  k_cast<<<64, 256, 0, stream>>>(w_out2, wbo2);

  k_nhwc<<<16384, 256, 0, stream>>>(x, xb);
  k_mconv1<<<1024, 256, 0, stream>>>(xb, wb1, nullptr, buf1, 1, stats);      // y1 + stats0
  k_mconv<<<1024, 256, 0, stream>>>(xb, wb2, buf2, 3, 6, stats + 256);       // y2 + stats1
  k_mconv<<<1024, 256, 0, stream>>>(xb, wb3, dbuf, 3, 12, stats + 512);      // y3 + stats2
  k_bnfin<<<1, 128, 0, stream>>>(stats, gd1, bd1, gd2, bd2, gd3, bd3, bnso);
  k_bnapply<<<8192, 256, 0, stream>>>(buf1, buf2, dbuf, bnso, sb);   // sb bf16 NHWC (xb dead)
  k_mconv1<<<1024, 256, 0, stream>>>(sb, wbo1, x, buf2, 0, nullptr); // out2 (y2 dead)
  k_ln<<<512, 256, 0, stream>>>(x, ln_w, ln_b, buf0);                // x1 (sb dead)
  k_dw2<<<4096, 256, 0, stream>>>(buf0, w1,b1,w2,b2,w3,b3,w4,b4,w5,b5,w6,b6, attb); // att bf16 (y3 dead)
  k_nhwcb<<<16384, 256, 0, stream>>>(attb, ab);                      // ab (y1 dead)
  k_mconv1<<<1024, 256, 0, stream>>>(ab, wbo2, nullptr, buf0, 0, nullptr);   // out1 (x1 dead)
  k_thx<<<32768, 256, 0, stream>>>(buf0, buf2, out1T, out2T, out1H, out2H,
                                   invn1h, invn1w, invn2w);          // T/H + norm partials
  k_finw<<<96, 256, 0, stream>>>(invn1h);                            // finalize all 3 norms
  k_attnS_m<<<128, 256, 0, stream>>>(out1T, out2T, out1H,
                                     invn1h, invn1w, invn2w, A1b, A2b);
  k_o34f<<<1024, 256, 0, stream>>>(A1b, out1T, out1H, invn1w,
                                   out2H, A2b, buf2, invn2w, o34b);  // o34 bf16 = o3+o4+q2+q1
  k_nhwcb<<<16384, 256, 0, stream>>>(o34b, ob);                      // ob (out1H dead)
  k_mconv1<<<1024, 256, 0, stream>>>(ob, wbo2, x, out, 0, nullptr);  // final + x (T dead)
}